// Round 8
// baseline (321.944 us; speedup 1.0000x reference)
//
#include <hip/hip_runtime.h>
#include <hip/hip_bf16.h>
#include <math.h>

#define NN 10000

typedef __attribute__((ext_vector_type(4))) float f32x4;
typedef __attribute__((ext_vector_type(8))) short short8v;

__device__ __forceinline__ short f2bf(float f) {
  union { float f; unsigned u; } v; v.f = f;
  unsigned u = v.u + 0x7FFFu + ((v.u >> 16) & 1u);  // RNE
  return (short)(u >> 16);
}
__device__ __forceinline__ float bf2f(unsigned short h) {
  union { unsigned u; float f; } v; v.u = ((unsigned)h) << 16;
  return v.f;
}
__device__ __forceinline__ float artanh_(float xx) {
  xx = fminf(fmaxf(xx, -1.f + 1e-7f), 1.f - 1e-7f);
  return atanhf(xx);
}
__device__ __forceinline__ void proj16(float* v) {
  float s = 0.f;
#pragma unroll
  for (int i = 0; i < 16; ++i) s += v[i] * v[i];
  float n = fmaxf(sqrtf(s), 1e-15f);
  const float mxn = 1.0f - 4e-3f;
  if (n > mxn) {
    float sc = mxn / n;
#pragma unroll
    for (int i = 0; i < 16; ++i) v[i] *= sc;
  }
}
__device__ __forceinline__ short8v cvt8(const float4& u, const float4& w) {
  union { __hip_bfloat162 h; unsigned u32; } c0, c1, c2, c3;
  c0.h = __float22bfloat162_rn(make_float2(u.x, u.y));
  c1.h = __float22bfloat162_rn(make_float2(u.z, u.w));
  c2.h = __float22bfloat162_rn(make_float2(w.x, w.y));
  c3.h = __float22bfloat162_rn(make_float2(w.z, w.w));
  union { unsigned v[4]; short8v s; } r;
  r.v[0] = c0.u32; r.v[1] = c1.u32; r.v[2] = c2.u32; r.v[3] = c3.u32;
  return r.s;
}

// ---------------- K1: pass over x -> rhs (both branches) + partial a; zero step-312 PB tail ----------------
__global__ __launch_bounds__(192) void k_attn1(
    const float* __restrict__ x,
    const float* __restrict__ U1a, const float* __restrict__ U3a,
    const float* __restrict__ U1b, const float* __restrict__ U3b,
    float* __restrict__ rhsA, float* __restrict__ rhsB,
    float* __restrict__ partAa, float* __restrict__ partAb,
    unsigned short* __restrict__ PB) {
  __shared__ float xs[16 * 193];
  int tid = threadIdx.x;
  int f_ = tid / 12, t_ = tid - f_ * 12;
  int s_ = tid >> 4, nl_ = tid & 15;
  // zero PB pad: frag-step 312, shorts [256,512) of each of its 12 frags (k >= 10000)
  if (blockIdx.x == 79) {
    for (int i = tid; i < 3072; i += 192) {
      int tt = i >> 8, q = i & 255;
      PB[(size_t)(312 * 12 + tt) * 512 + 256 + q] = 0;
    }
  }
  float paa = 0.f, pab = 0.f;
  for (int tb = blockIdx.x; tb < 625; tb += 160) {
    int n0 = tb * 16;
    for (int i = tid; i < 16 * 192; i += 192) {
      int a = i / 192, j = i - a * 192;
      xs[a * 193 + j] = x[(size_t)(n0 + a) * 192 + j];
    }
    __syncthreads();
    float ra = 0.f, rb = 0.f;
#pragma unroll
    for (int f = 0; f < 16; ++f) {
      float xv = xs[nl_ * 193 + f * 12 + s_];
      ra += xv * U3a[f];
      rb += xv * U3b[f];
    }
    rhsA[s_ * NN + n0 + nl_] = ra;
    rhsB[s_ * NN + n0 + nl_] = rb;
#pragma unroll
    for (int nl = 0; nl < 16; ++nl) {
      float xv = xs[nl * 193 + f_ * 12 + t_];
      paa += xv * U1a[n0 + nl];
      pab += xv * U1b[n0 + nl];
    }
    __syncthreads();
  }
  partAa[blockIdx.x * 192 + tid] = paa;
  partAb[blockIdx.x * 192 + tid] = pab;
}

// ---------------- K2: M[f,s] partials; also zero PB pad steps 313..323 ----------------
__global__ __launch_bounds__(192) void k_attn2(
    const float* __restrict__ U2a, const float* __restrict__ U2b,
    const float* __restrict__ rhsA, const float* __restrict__ rhsB,
    float* __restrict__ partMa, float* __restrict__ partMb,
    unsigned short* __restrict__ PB) {
  int tid = threadIdx.x;
  // pad region: shorts [313*6144, 324*6144) = 67584 shorts, contiguous
  for (int i = tid; i < 960; i += 192) {
    int idx = blockIdx.x * 960 + i;
    if (idx < 67584) PB[1923072 + idx] = 0;
  }
  int f = tid / 12, s = tid - f * 12;
  int nA = blockIdx.x * 125, nE = nA + 125;
  float ma = 0.f, mb = 0.f;
  for (int n = nA; n < nE; ++n) {
    ma += U2a[f * NN + n] * rhsA[s * NN + n];
    mb += U2b[f * NN + n] * rhsB[s * NN + n];
  }
  partMa[blockIdx.x * 192 + tid] = ma;
  partMb[blockIdx.x * 192 + tid] = mb;
}

// ---------------- K3: reduce partials, product, E, softmax -> tA (both) ----------------
__global__ __launch_bounds__(192) void k_attn3(
    const float* __restrict__ partAa, const float* __restrict__ partAb,
    const float* __restrict__ partMa, const float* __restrict__ partMb,
    const float* __restrict__ beA, const float* __restrict__ VeA,
    const float* __restrict__ beB, const float* __restrict__ VeB,
    float* __restrict__ tAa, float* __restrict__ tAb) {
  __shared__ float aa[192], ab[192], Ma[192], Mb[192];
  __shared__ float spA[144], spB[144], EA[144], EB[144];
  int tid = threadIdx.x;
  float s1 = 0.f, s2 = 0.f, s3 = 0.f, s4 = 0.f;
  for (int b = 0; b < 160; ++b) { s1 += partAa[b * 192 + tid]; s2 += partAb[b * 192 + tid]; }
  for (int b = 0; b < 80; ++b) { s3 += partMa[b * 192 + tid]; s4 += partMb[b * 192 + tid]; }
  aa[tid] = s1; ab[tid] = s2; Ma[tid] = s3; Mb[tid] = s4;
  __syncthreads();
  if (tid < 144) {
    int j = tid / 12, s = tid - j * 12;
    float pa = 0.f, pb = 0.f;
#pragma unroll
    for (int f = 0; f < 16; ++f) {
      pa += aa[f * 12 + j] * Ma[f * 12 + s];
      pb += ab[f * 12 + j] * Mb[f * 12 + s];
    }
    spA[tid] = 1.f / (1.f + expf(-(pa + beA[tid])));
    spB[tid] = 1.f / (1.f + expf(-(pb + beB[tid])));
  }
  __syncthreads();
  if (tid < 144) {
    int i = tid / 12, s = tid - i * 12;
    float ea = 0.f, eb = 0.f;
#pragma unroll
    for (int j = 0; j < 12; ++j) {
      ea += VeA[i * 12 + j] * spA[j * 12 + s];
      eb += VeB[i * 12 + j] * spB[j * 12 + s];
    }
    EA[tid] = ea; EB[tid] = eb;
  }
  __syncthreads();
  if (tid < 144) {
    int s = tid % 12;
    float ma = -1e30f, mb = -1e30f;
#pragma unroll
    for (int k = 0; k < 12; ++k) { ma = fmaxf(ma, EA[k * 12 + s]); mb = fmaxf(mb, EB[k * 12 + s]); }
    float da = 0.f, db = 0.f;
#pragma unroll
    for (int k = 0; k < 12; ++k) { da += expf(EA[k * 12 + s] - ma); db += expf(EB[k * 12 + s] - mb); }
    tAa[tid] = expf(EA[tid] - ma) / da;
    tAb[tid] = expf(EB[tid] - mb) / db;
  }
}

// ---------------- K4: per-node x_tat + conv (both) + hyperbolic -> PB (lane-ordered B frags), outF ----------------
__global__ __launch_bounds__(192) void k_node(
    const float* __restrict__ x,
    const float* __restrict__ tAa_g, const float* __restrict__ tAb_g,
    const float* __restrict__ w1g, const float* __restrict__ b1g,
    const float* __restrict__ w2g, const float* __restrict__ b2g,
    const float* __restrict__ hwg, const float* __restrict__ hbg,
    float* __restrict__ outF, unsigned short* __restrict__ PB) {
  __shared__ float xs[16 * 193], tbuf[16 * 193];
  __shared__ float tAa[144], tAb[144], w1[768], w2[768];
  __shared__ float cb1[16], cb2[16], hw[256], hbr[16];
  int tid = threadIdx.x;
  int nl = tid & 15, tt = tid >> 4;
  int n0 = blockIdx.x * 16;
  for (int i = tid; i < 144; i += 192) { tAa[i] = tAa_g[i]; tAb[i] = tAb_g[i]; }
  for (int i = tid; i < 768; i += 192) { w1[i] = w1g[i]; w2[i] = w2g[i]; }
  for (int i = tid; i < 256; i += 192) hw[i] = hwg[i];
  if (tid < 16) { cb1[tid] = b1g[tid]; cb2[tid] = b2g[tid]; hbr[tid] = hbg[tid]; }
  for (int i = tid; i < 16 * 192; i += 192) {
    int a = i / 192, j = i - a * 192;
    xs[a * 193 + j] = x[(size_t)(n0 + a) * 192 + j];
  }
  __syncthreads();

  float z[16];
  // ======== branch b (second attention -> conv2 -> final_output) ========
#pragma unroll
  for (int f = 0; f < 16; ++f) {
    float v = 0.f;
#pragma unroll
    for (int s = 0; s < 12; ++s) v += xs[nl * 193 + f * 12 + s] * tAb[s * 12 + tt];
    tbuf[nl * 193 + f * 12 + tt] = v;
  }
  __syncthreads();
#pragma unroll
  for (int o = 0; o < 16; ++o) z[o] = cb2[o];
#pragma unroll
  for (int k = 0; k < 3; ++k) {
    int t2 = tt + k - 1;
    if (t2 >= 0 && t2 < 12) {
#pragma unroll
      for (int i = 0; i < 16; ++i) {
        float xv = tbuf[nl * 193 + i * 12 + t2];
#pragma unroll
        for (int o = 0; o < 16; ++o) z[o] += xv * w2[o * 48 + i * 3 + k];
      }
    }
  }
  {
    float* op = outF + (size_t)tt * (NN * 16) + (size_t)(n0 + nl) * 16;
#pragma unroll
    for (int o = 0; o < 16; ++o) op[o] = z[o];
  }
  __syncthreads();

  // ======== branch a (first attention -> conv1 -> hyperbolic -> xt) ========
#pragma unroll
  for (int f = 0; f < 16; ++f) {
    float v = 0.f;
#pragma unroll
    for (int s = 0; s < 12; ++s) v += xs[nl * 193 + f * 12 + s] * tAa[s * 12 + tt];
    tbuf[nl * 193 + f * 12 + tt] = v;
  }
  __syncthreads();
#pragma unroll
  for (int o = 0; o < 16; ++o) z[o] = cb1[o];
#pragma unroll
  for (int k = 0; k < 3; ++k) {
    int t2 = tt + k - 1;
    if (t2 >= 0 && t2 < 12) {
#pragma unroll
      for (int i = 0; i < 16; ++i) {
        float xv = tbuf[nl * 193 + i * 12 + t2];
#pragma unroll
        for (int o = 0; o < 16; ++o) z[o] += xv * w1[o * 48 + i * 3 + k];
      }
    }
  }
  // x_hyp = proj(expmap0(z))
  float nz = 0.f;
#pragma unroll
  for (int i = 0; i < 16; ++i) nz += z[i] * z[i];
  nz = fmaxf(sqrtf(nz), 1e-15f);
  float sc0 = tanhf(nz) / nz;
#pragma unroll
  for (int i = 0; i < 16; ++i) z[i] *= sc0;
  proj16(z);
  // mobius_matvec(hgc_w, x_hyp)
  float xn = 0.f;
#pragma unroll
  for (int i = 0; i < 16; ++i) xn += z[i] * z[i];
  xn = fmaxf(sqrtf(xn), 1e-15f);
  float mx[16];
#pragma unroll
  for (int d = 0; d < 16; ++d) {
    float v = 0.f;
#pragma unroll
    for (int f = 0; f < 16; ++f) v += z[f] * hw[d * 16 + f];
    mx[d] = v;
  }
  float mxr = 0.f;
#pragma unroll
  for (int d = 0; d < 16; ++d) mxr += mx[d] * mx[d];
  mxr = sqrtf(mxr);
  float mxn = fmaxf(mxr, 1e-15f);
  float rs = tanhf(mxn / xn * artanh_(xn)) / mxn;
  if (mxr == 0.f) rs = 0.f;
#pragma unroll
  for (int d = 0; d < 16; ++d) mx[d] *= rs;
  proj16(mx);
  // hyp_b = proj(expmap0(hgc_b))
  float hb[16];
  float bn = 0.f;
#pragma unroll
  for (int i = 0; i < 16; ++i) { hb[i] = hbr[i]; bn += hb[i] * hb[i]; }
  bn = fmaxf(sqrtf(bn), 1e-15f);
  float sb = tanhf(bn) / bn;
#pragma unroll
  for (int i = 0; i < 16; ++i) hb[i] *= sb;
  proj16(hb);
  // res = proj(mobius_add(mx, hb))
  float x2 = 0.f, y2 = 0.f, xy = 0.f;
#pragma unroll
  for (int i = 0; i < 16; ++i) { x2 += mx[i] * mx[i]; y2 += hb[i] * hb[i]; xy += mx[i] * hb[i]; }
  float ca = 1.f + 2.f * xy + y2;
  float cbv = 1.f - x2;
  float den = fmaxf(1.f + 2.f * xy + x2 * y2, 1e-15f);
#pragma unroll
  for (int i = 0; i < 16; ++i) mx[i] = (ca * mx[i] + cbv * hb[i]) / den;
  proj16(mx);
  // xt = logmap0(res) -> PB in MFMA lane order:
  // PB[frag*512 + lane*8 + j] = B[k=(lane>>4)*8+j][col=lane&15]
  float pn = 0.f;
#pragma unroll
  for (int i = 0; i < 16; ++i) pn += mx[i] * mx[i];
  pn = fmaxf(sqrtf(pn), 1e-15f);
  float sl = artanh_(pn) / pn;
  {
    int nn2 = n0 + nl;
    int s = nn2 >> 5, c = nn2 & 31;
    unsigned short* pp = PB + (size_t)(s * 12 + tt) * 512 + (c >> 3) * 128 + (c & 7);
#pragma unroll
    for (int d = 0; d < 16; ++d)
      pp[d * 8] = (unsigned short)f2bf(mx[d] * sl);
  }
}

// ---------------- K5: sup = adj @ xt — ZERO-LDS register-pipelined MFMA, plain loads, no barriers ----------------
// grid = NC x 313 row-tiles; 64 threads (1 wave) per block; wave owns 32 rows x all 192 features.
// A: 4 global_load_dwordx4/step (per lane 32 B contiguous), double-buffered 2 steps ahead.
// B: 12 global_load_dwordx4/step (1 KB contiguous each), single-buffered, issued right after consume.
// Compiler inserts all waitcnts; no LDS, no __syncthreads in the K-loop.
__global__ __launch_bounds__(64) void k_gemm(
    const float* __restrict__ adj, const unsigned short* __restrict__ PB,
    unsigned short* __restrict__ partC, int S) {
  int bc = blockIdx.x / 313;
  int rt = blockIdx.x - bc * 313;
  int g0 = bc * S, g1 = min(g0 + S, 320);  // steps are even-count per chunk
  int lane = threadIdx.x;
  int r0 = lane & 15, kq = lane >> 4;
  int R0 = rt * 32;
  int row0 = min(R0 + r0, NN - 1), row1 = min(R0 + 16 + r0, NN - 1);
  const float* pa0 = adj + (size_t)row0 * NN;
  const float* pa1 = adj + (size_t)row1 * NN;
  int cq = kq * 8;

  f32x4 acc0[12], acc1[12];
  f32x4 zz = {0.f, 0.f, 0.f, 0.f};
#pragma unroll
  for (int j = 0; j < 12; ++j) { acc0[j] = zz; acc1[j] = zz; }

  auto LA = [&](int t, float4* a) {
    int col = t * 32 + cq;
    if (col + 8 > NN) col = 0;  // K-tail / overrun: multiplies zero-padded B slots
    a[0] = *(const float4*)(pa0 + col);
    a[1] = *(const float4*)(pa0 + col + 4);
    a[2] = *(const float4*)(pa1 + col);
    a[3] = *(const float4*)(pa1 + col + 4);
  };
  auto LB = [&](int t, short8v* b) {
    const short8v* g = (const short8v*)(PB + (size_t)t * 6144) + lane;
#pragma unroll
    for (int j = 0; j < 12; ++j) b[j] = g[j * 64];
  };
  auto MMX = [&](const float4* a, const short8v* b) {
    short8v f0 = cvt8(a[0], a[1]);
    short8v f1 = cvt8(a[2], a[3]);
#pragma unroll
    for (int j = 0; j < 12; ++j) {
      acc0[j] = __builtin_amdgcn_mfma_f32_16x16x32_bf16(f0, b[j], acc0[j], 0, 0, 0);
      acc1[j] = __builtin_amdgcn_mfma_f32_16x16x32_bf16(f1, b[j], acc1[j], 0, 0, 0);
    }
  };

  float4 xa[4], ya[4];
  short8v bb[12];
  LB(g0, bb);
  LA(g0, xa);
  LA(g0 + 1, ya);
  for (int t = g0; t < g1; t += 2) {
    MMX(xa, bb);           // consume step t
    LB(t + 1, bb);         // B for t+1 (PB padded through step 323)
    LA(t + 2, xa);         // A for t+2
    MMX(ya, bb);           // consume step t+1
    LB(t + 2, bb);
    LA(t + 3, ya);
  }

  // epilogue: D layout col(lane&15)=feature, row(M)=kq*4+r
  size_t cbase = (size_t)bc * ((size_t)NN * 192);
  int drow = kq * 4;
#pragma unroll
  for (int j = 0; j < 12; ++j) {
#pragma unroll
    for (int r = 0; r < 4; ++r) {
      int rw0 = R0 + drow + r;
      int rw1 = R0 + 16 + drow + r;
      if (rw0 < NN)
        partC[cbase + (size_t)rw0 * 192 + j * 16 + r0] = (unsigned short)f2bf(acc0[j][r]);
      if (rw1 < NN)
        partC[cbase + (size_t)rw1 * 192 + j * 16 + r0] = (unsigned short)f2bf(acc1[j][r]);
    }
  }
}

// ---------------- K6: reduce partials + hyperbolic epilogue -> h ----------------
__global__ __launch_bounds__(256) void k_epi(const unsigned short* __restrict__ partC,
                                             float* __restrict__ outH, int NC) {
  int gid = blockIdx.x * 256 + threadIdx.x;
  if (gid >= NN * 12) return;
  int n = gid / 12, t = gid - n * 12;
  float sup[16];
#pragma unroll
  for (int d = 0; d < 16; ++d) sup[d] = 0.f;
  for (int c = 0; c < NC; ++c) {
    const short8v* p8 = (const short8v*)(partC + (size_t)c * (NN * 192) + (size_t)n * 192 + t * 16);
    short8v lo = p8[0], hi = p8[1];
#pragma unroll
    for (int d = 0; d < 8; ++d) sup[d] += bf2f((unsigned short)lo[d]);
#pragma unroll
    for (int d = 0; d < 8; ++d) sup[8 + d] += bf2f((unsigned short)hi[d]);
  }
  // agg = proj(expmap0(sup))
  float nn_ = 0.f;
#pragma unroll
  for (int d = 0; d < 16; ++d) nn_ += sup[d] * sup[d];
  nn_ = fmaxf(sqrtf(nn_), 1e-15f);
  float s0 = tanhf(nn_) / nn_;
#pragma unroll
  for (int d = 0; d < 16; ++d) sup[d] *= s0;
  proj16(sup);
  // relu(logmap0(agg))
  float pn = 0.f;
#pragma unroll
  for (int d = 0; d < 16; ++d) pn += sup[d] * sup[d];
  pn = fmaxf(sqrtf(pn), 1e-15f);
  float sl = artanh_(pn) / pn;
#pragma unroll
  for (int d = 0; d < 16; ++d) sup[d] = fmaxf(sup[d] * sl, 0.f);
  // proj(expmap0(...))
  float un = 0.f;
#pragma unroll
  for (int d = 0; d < 16; ++d) un += sup[d] * sup[d];
  un = fmaxf(sqrtf(un), 1e-15f);
  float se = tanhf(un) / un;
#pragma unroll
  for (int d = 0; d < 16; ++d) sup[d] *= se;
  proj16(sup);
  float* hp = outH + (size_t)n * 192 + t;  // h[n][d][t]
#pragma unroll
  for (int d = 0; d < 16; ++d) hp[d * 12] = sup[d];
}

extern "C" void kernel_launch(void* const* d_in, const int* in_sizes, int n_in,
                              void* d_out, int out_size, void* d_ws, size_t ws_size,
                              hipStream_t stream) {
  const float* x   = (const float*)d_in[0];
  const float* adj = (const float*)d_in[1];
  const float* U1a = (const float*)d_in[2];
  const float* U2a = (const float*)d_in[3];
  const float* U3a = (const float*)d_in[4];
  const float* bea = (const float*)d_in[5];
  const float* Vea = (const float*)d_in[6];
  const float* U1b = (const float*)d_in[7];
  const float* U2b = (const float*)d_in[8];
  const float* U3b = (const float*)d_in[9];
  const float* beb = (const float*)d_in[10];
  const float* Veb = (const float*)d_in[11];
  const float* w1  = (const float*)d_in[12];
  const float* b1  = (const float*)d_in[13];
  const float* w2  = (const float*)d_in[14];
  const float* b2  = (const float*)d_in[15];
  const float* hw  = (const float*)d_in[16];
  const float* hb  = (const float*)d_in[17];
  float* outF = (float*)d_out;
  float* outH = (float*)d_out + 1920000;

  char* ws = (char*)d_ws;
  size_t off = 0;
  auto alloc = [&](size_t bytes) {
    char* p = ws + off;
    off = (off + bytes + 255) & ~(size_t)255;
    return p;
  };
  float* rhsA   = (float*)alloc((size_t)12 * NN * 4);
  float* rhsB   = (float*)alloc((size_t)12 * NN * 4);
  float* partAa = (float*)alloc(160 * 192 * 4);
  float* partAb = (float*)alloc(160 * 192 * 4);
  float* partMa = (float*)alloc(80 * 192 * 4);
  float* partMb = (float*)alloc(80 * 192 * 4);
  float* tAa    = (float*)alloc(144 * 4);
  float* tAb    = (float*)alloc(144 * 4);
  unsigned short* PB = (unsigned short*)alloc((size_t)324 * 6144 * 2);  // padded to 324 steps
  size_t chunkB = (size_t)NN * 192 * 2;
  size_t avail = (ws_size > off) ? (ws_size - off) : 0;
  int NC = (int)(avail / chunkB);
  if (NC > 8) NC = 8;
  if (NC < 1) NC = 1;
  unsigned short* partC = (unsigned short*)(ws + off);
  int S = ((320 + NC - 1) / NC + 1) & ~1;  // even step-count per chunk (K padded to 320 steps)

  k_attn1<<<160, 192, 0, stream>>>(x, U1a, U3a, U1b, U3b, rhsA, rhsB, partAa, partAb, PB);
  k_attn2<<<80, 192, 0, stream>>>(U2a, U2b, rhsA, rhsB, partMa, partMb, PB);
  k_attn3<<<1, 192, 0, stream>>>(partAa, partAb, partMa, partMb, bea, Vea, beb, Veb, tAa, tAb);
  k_node<<<625, 192, 0, stream>>>(x, tAa, tAb, w1, b1, w2, b2, hw, hb, outF, PB);
  k_gemm<<<313 * NC, 64, 0, stream>>>(adj, PB, partC, S);
  k_epi<<<(NN * 12 + 255) / 256, 256, 0, stream>>>(partC, outH, NC);
}

// Round 9
// 273.186 us; speedup vs baseline: 1.1785x; 1.1785x over previous
//
#include <hip/hip_runtime.h>
#include <hip/hip_bf16.h>
#include <math.h>

#define NN 10000

typedef __attribute__((ext_vector_type(4))) float f32x4;
typedef __attribute__((ext_vector_type(8))) short short8v;

__device__ __forceinline__ short f2bf(float f) {
  union { float f; unsigned u; } v; v.f = f;
  unsigned u = v.u + 0x7FFFu + ((v.u >> 16) & 1u);  // RNE
  return (short)(u >> 16);
}
__device__ __forceinline__ float bf2f(unsigned short h) {
  union { unsigned u; float f; } v; v.u = ((unsigned)h) << 16;
  return v.f;
}
__device__ __forceinline__ float artanh_(float xx) {
  xx = fminf(fmaxf(xx, -1.f + 1e-7f), 1.f - 1e-7f);
  return atanhf(xx);
}
__device__ __forceinline__ void proj16(float* v) {
  float s = 0.f;
#pragma unroll
  for (int i = 0; i < 16; ++i) s += v[i] * v[i];
  float n = fmaxf(sqrtf(s), 1e-15f);
  const float mxn = 1.0f - 4e-3f;
  if (n > mxn) {
    float sc = mxn / n;
#pragma unroll
    for (int i = 0; i < 16; ++i) v[i] *= sc;
  }
}
__device__ __forceinline__ short8v cvt8(const float4& u, const float4& w) {
  union { __hip_bfloat162 h; unsigned u32; } c0, c1, c2, c3;
  c0.h = __float22bfloat162_rn(make_float2(u.x, u.y));
  c1.h = __float22bfloat162_rn(make_float2(u.z, u.w));
  c2.h = __float22bfloat162_rn(make_float2(w.x, w.y));
  c3.h = __float22bfloat162_rn(make_float2(w.z, w.w));
  union { unsigned v[4]; short8v s; } r;
  r.v[0] = c0.u32; r.v[1] = c1.u32; r.v[2] = c2.u32; r.v[3] = c3.u32;
  return r.s;
}

// ---------------- K1: pass over x -> rhs (both branches) + partial a; zero step-312 PB tail ----------------
__global__ __launch_bounds__(192) void k_attn1(
    const float* __restrict__ x,
    const float* __restrict__ U1a, const float* __restrict__ U3a,
    const float* __restrict__ U1b, const float* __restrict__ U3b,
    float* __restrict__ rhsA, float* __restrict__ rhsB,
    float* __restrict__ partAa, float* __restrict__ partAb,
    unsigned short* __restrict__ PB) {
  __shared__ float xs[16 * 193];
  int tid = threadIdx.x;
  int f_ = tid / 12, t_ = tid - f_ * 12;
  int s_ = tid >> 4, nl_ = tid & 15;
  // zero PB pad: frag-step 312, shorts [256,512) of each of its 12 frags (k >= 10000)
  if (blockIdx.x == 79) {
    for (int i = tid; i < 3072; i += 192) {
      int tt = i >> 8, q = i & 255;
      PB[(size_t)(312 * 12 + tt) * 512 + 256 + q] = 0;
    }
  }
  float paa = 0.f, pab = 0.f;
  for (int tb = blockIdx.x; tb < 625; tb += 160) {
    int n0 = tb * 16;
    for (int i = tid; i < 16 * 192; i += 192) {
      int a = i / 192, j = i - a * 192;
      xs[a * 193 + j] = x[(size_t)(n0 + a) * 192 + j];
    }
    __syncthreads();
    float ra = 0.f, rb = 0.f;
#pragma unroll
    for (int f = 0; f < 16; ++f) {
      float xv = xs[nl_ * 193 + f * 12 + s_];
      ra += xv * U3a[f];
      rb += xv * U3b[f];
    }
    rhsA[s_ * NN + n0 + nl_] = ra;
    rhsB[s_ * NN + n0 + nl_] = rb;
#pragma unroll
    for (int nl = 0; nl < 16; ++nl) {
      float xv = xs[nl * 193 + f_ * 12 + t_];
      paa += xv * U1a[n0 + nl];
      pab += xv * U1b[n0 + nl];
    }
    __syncthreads();
  }
  partAa[blockIdx.x * 192 + tid] = paa;
  partAb[blockIdx.x * 192 + tid] = pab;
}

// ---------------- K2: M[f,s] partials; also zero PB pad steps 313..323 ----------------
__global__ __launch_bounds__(192) void k_attn2(
    const float* __restrict__ U2a, const float* __restrict__ U2b,
    const float* __restrict__ rhsA, const float* __restrict__ rhsB,
    float* __restrict__ partMa, float* __restrict__ partMb,
    unsigned short* __restrict__ PB) {
  int tid = threadIdx.x;
  // pad region: shorts [313*6144, 324*6144) = 67584 shorts, contiguous
  for (int i = tid; i < 960; i += 192) {
    int idx = blockIdx.x * 960 + i;
    if (idx < 67584) PB[1923072 + idx] = 0;
  }
  int f = tid / 12, s = tid - f * 12;
  int nA = blockIdx.x * 125, nE = nA + 125;
  float ma = 0.f, mb = 0.f;
  for (int n = nA; n < nE; ++n) {
    ma += U2a[f * NN + n] * rhsA[s * NN + n];
    mb += U2b[f * NN + n] * rhsB[s * NN + n];
  }
  partMa[blockIdx.x * 192 + tid] = ma;
  partMb[blockIdx.x * 192 + tid] = mb;
}

// ---------------- K3: reduce partials, product, E, softmax -> tA (both) ----------------
__global__ __launch_bounds__(192) void k_attn3(
    const float* __restrict__ partAa, const float* __restrict__ partAb,
    const float* __restrict__ partMa, const float* __restrict__ partMb,
    const float* __restrict__ beA, const float* __restrict__ VeA,
    const float* __restrict__ beB, const float* __restrict__ VeB,
    float* __restrict__ tAa, float* __restrict__ tAb) {
  __shared__ float aa[192], ab[192], Ma[192], Mb[192];
  __shared__ float spA[144], spB[144], EA[144], EB[144];
  int tid = threadIdx.x;
  float s1 = 0.f, s2 = 0.f, s3 = 0.f, s4 = 0.f;
  for (int b = 0; b < 160; ++b) { s1 += partAa[b * 192 + tid]; s2 += partAb[b * 192 + tid]; }
  for (int b = 0; b < 80; ++b) { s3 += partMa[b * 192 + tid]; s4 += partMb[b * 192 + tid]; }
  aa[tid] = s1; ab[tid] = s2; Ma[tid] = s3; Mb[tid] = s4;
  __syncthreads();
  if (tid < 144) {
    int j = tid / 12, s = tid - j * 12;
    float pa = 0.f, pb = 0.f;
#pragma unroll
    for (int f = 0; f < 16; ++f) {
      pa += aa[f * 12 + j] * Ma[f * 12 + s];
      pb += ab[f * 12 + j] * Mb[f * 12 + s];
    }
    spA[tid] = 1.f / (1.f + expf(-(pa + beA[tid])));
    spB[tid] = 1.f / (1.f + expf(-(pb + beB[tid])));
  }
  __syncthreads();
  if (tid < 144) {
    int i = tid / 12, s = tid - i * 12;
    float ea = 0.f, eb = 0.f;
#pragma unroll
    for (int j = 0; j < 12; ++j) {
      ea += VeA[i * 12 + j] * spA[j * 12 + s];
      eb += VeB[i * 12 + j] * spB[j * 12 + s];
    }
    EA[tid] = ea; EB[tid] = eb;
  }
  __syncthreads();
  if (tid < 144) {
    int s = tid % 12;
    float ma = -1e30f, mb = -1e30f;
#pragma unroll
    for (int k = 0; k < 12; ++k) { ma = fmaxf(ma, EA[k * 12 + s]); mb = fmaxf(mb, EB[k * 12 + s]); }
    float da = 0.f, db = 0.f;
#pragma unroll
    for (int k = 0; k < 12; ++k) { da += expf(EA[k * 12 + s] - ma); db += expf(EB[k * 12 + s] - mb); }
    tAa[tid] = expf(EA[tid] - ma) / da;
    tAb[tid] = expf(EB[tid] - mb) / db;
  }
}

// ---------------- K4: per-node x_tat + conv (both) + hyperbolic -> PB (lane-ordered B frags), outF ----------------
__global__ __launch_bounds__(192) void k_node(
    const float* __restrict__ x,
    const float* __restrict__ tAa_g, const float* __restrict__ tAb_g,
    const float* __restrict__ w1g, const float* __restrict__ b1g,
    const float* __restrict__ w2g, const float* __restrict__ b2g,
    const float* __restrict__ hwg, const float* __restrict__ hbg,
    float* __restrict__ outF, unsigned short* __restrict__ PB) {
  __shared__ float xs[16 * 193], tbuf[16 * 193];
  __shared__ float tAa[144], tAb[144], w1[768], w2[768];
  __shared__ float cb1[16], cb2[16], hw[256], hbr[16];
  int tid = threadIdx.x;
  int nl = tid & 15, tt = tid >> 4;
  int n0 = blockIdx.x * 16;
  for (int i = tid; i < 144; i += 192) { tAa[i] = tAa_g[i]; tAb[i] = tAb_g[i]; }
  for (int i = tid; i < 768; i += 192) { w1[i] = w1g[i]; w2[i] = w2g[i]; }
  for (int i = tid; i < 256; i += 192) hw[i] = hwg[i];
  if (tid < 16) { cb1[tid] = b1g[tid]; cb2[tid] = b2g[tid]; hbr[tid] = hbg[tid]; }
  for (int i = tid; i < 16 * 192; i += 192) {
    int a = i / 192, j = i - a * 192;
    xs[a * 193 + j] = x[(size_t)(n0 + a) * 192 + j];
  }
  __syncthreads();

  float z[16];
  // ======== branch b (second attention -> conv2 -> final_output) ========
#pragma unroll
  for (int f = 0; f < 16; ++f) {
    float v = 0.f;
#pragma unroll
    for (int s = 0; s < 12; ++s) v += xs[nl * 193 + f * 12 + s] * tAb[s * 12 + tt];
    tbuf[nl * 193 + f * 12 + tt] = v;
  }
  __syncthreads();
#pragma unroll
  for (int o = 0; o < 16; ++o) z[o] = cb2[o];
#pragma unroll
  for (int k = 0; k < 3; ++k) {
    int t2 = tt + k - 1;
    if (t2 >= 0 && t2 < 12) {
#pragma unroll
      for (int i = 0; i < 16; ++i) {
        float xv = tbuf[nl * 193 + i * 12 + t2];
#pragma unroll
        for (int o = 0; o < 16; ++o) z[o] += xv * w2[o * 48 + i * 3 + k];
      }
    }
  }
  {
    float* op = outF + (size_t)tt * (NN * 16) + (size_t)(n0 + nl) * 16;
#pragma unroll
    for (int o = 0; o < 16; ++o) op[o] = z[o];
  }
  __syncthreads();

  // ======== branch a (first attention -> conv1 -> hyperbolic -> xt) ========
#pragma unroll
  for (int f = 0; f < 16; ++f) {
    float v = 0.f;
#pragma unroll
    for (int s = 0; s < 12; ++s) v += xs[nl * 193 + f * 12 + s] * tAa[s * 12 + tt];
    tbuf[nl * 193 + f * 12 + tt] = v;
  }
  __syncthreads();
#pragma unroll
  for (int o = 0; o < 16; ++o) z[o] = cb1[o];
#pragma unroll
  for (int k = 0; k < 3; ++k) {
    int t2 = tt + k - 1;
    if (t2 >= 0 && t2 < 12) {
#pragma unroll
      for (int i = 0; i < 16; ++i) {
        float xv = tbuf[nl * 193 + i * 12 + t2];
#pragma unroll
        for (int o = 0; o < 16; ++o) z[o] += xv * w1[o * 48 + i * 3 + k];
      }
    }
  }
  // x_hyp = proj(expmap0(z))
  float nz = 0.f;
#pragma unroll
  for (int i = 0; i < 16; ++i) nz += z[i] * z[i];
  nz = fmaxf(sqrtf(nz), 1e-15f);
  float sc0 = tanhf(nz) / nz;
#pragma unroll
  for (int i = 0; i < 16; ++i) z[i] *= sc0;
  proj16(z);
  // mobius_matvec(hgc_w, x_hyp)
  float xn = 0.f;
#pragma unroll
  for (int i = 0; i < 16; ++i) xn += z[i] * z[i];
  xn = fmaxf(sqrtf(xn), 1e-15f);
  float mx[16];
#pragma unroll
  for (int d = 0; d < 16; ++d) {
    float v = 0.f;
#pragma unroll
    for (int f = 0; f < 16; ++f) v += z[f] * hw[d * 16 + f];
    mx[d] = v;
  }
  float mxr = 0.f;
#pragma unroll
  for (int d = 0; d < 16; ++d) mxr += mx[d] * mx[d];
  mxr = sqrtf(mxr);
  float mxn = fmaxf(mxr, 1e-15f);
  float rs = tanhf(mxn / xn * artanh_(xn)) / mxn;
  if (mxr == 0.f) rs = 0.f;
#pragma unroll
  for (int d = 0; d < 16; ++d) mx[d] *= rs;
  proj16(mx);
  // hyp_b = proj(expmap0(hgc_b))
  float hb[16];
  float bn = 0.f;
#pragma unroll
  for (int i = 0; i < 16; ++i) { hb[i] = hbr[i]; bn += hb[i] * hb[i]; }
  bn = fmaxf(sqrtf(bn), 1e-15f);
  float sb = tanhf(bn) / bn;
#pragma unroll
  for (int i = 0; i < 16; ++i) hb[i] *= sb;
  proj16(hb);
  // res = proj(mobius_add(mx, hb))
  float x2 = 0.f, y2 = 0.f, xy = 0.f;
#pragma unroll
  for (int i = 0; i < 16; ++i) { x2 += mx[i] * mx[i]; y2 += hb[i] * hb[i]; xy += mx[i] * hb[i]; }
  float ca = 1.f + 2.f * xy + y2;
  float cbv = 1.f - x2;
  float den = fmaxf(1.f + 2.f * xy + x2 * y2, 1e-15f);
#pragma unroll
  for (int i = 0; i < 16; ++i) mx[i] = (ca * mx[i] + cbv * hb[i]) / den;
  proj16(mx);
  // xt = logmap0(res) -> PB in MFMA lane order:
  // PB[frag*512 + lane*8 + j] = B[k=(lane>>4)*8+j][col=lane&15]
  float pn = 0.f;
#pragma unroll
  for (int i = 0; i < 16; ++i) pn += mx[i] * mx[i];
  pn = fmaxf(sqrtf(pn), 1e-15f);
  float sl = artanh_(pn) / pn;
  {
    int nn2 = n0 + nl;
    int s = nn2 >> 5, c = nn2 & 31;
    unsigned short* pp = PB + (size_t)(s * 12 + tt) * 512 + (c >> 3) * 128 + (c & 7);
#pragma unroll
    for (int d = 0; d < 16; ++d)
      pp[d * 8] = (unsigned short)f2bf(mx[d] * sl);
  }
}

// ---------------- K5: sup = adj @ xt — BM=192, 6 waves, counted-vmcnt double-buffer, no drains ----------------
// grid = NC x 53 row-tiles; 384 threads (6 waves x 32 rows). Per step each wave issues exactly
// 6 global_load_lds (4 A for its 32-row slab + 2 B frags). LDS = 2 x (24KB A + 12KB B) = 72KB.
// Loop: vmcnt(6) -> barrier -> MFMA -> lgkmcnt(0) -> barrier -> STAGE(t+2). Loads never drained.
__global__ __launch_bounds__(384, 3) void k_gemm(
    const float* __restrict__ adj, const unsigned short* __restrict__ PB,
    unsigned short* __restrict__ partC, int S) {
  extern __shared__ char smem[];  // [buf][ A 6x4096 | B 12x1024 ] ; buf stride 36864
  int tid = threadIdx.x;
  int w = tid >> 6, lane = tid & 63;
  int bc = blockIdx.x / 53;
  int rt = blockIdx.x - bc * 53;
  int t0 = bc * S, t1 = min(t0 + S, 313);
  int ns = t1 - t0;
  int r0 = lane & 15, kq = lane >> 4;
  int R0w = rt * 192 + w * 32;

  // A staging: 4 instrs/wave; instr i, lane l covers wave-local row i*8+(l>>3), 16B at swizzled col
  int lhi = lane >> 3, llo = lane & 7;
  int arow[4], acolB[4];
#pragma unroll
  for (int i = 0; i < 4; ++i) {
    int row = i * 8 + lhi;
    arow[i] = min(R0w + row, NN - 1);
    acolB[i] = (llo * 16) ^ ((row & 7) << 4);  // swizzled byte offset in 128B row window
  }

  f32x4 acc0[12], acc1[12];
  f32x4 zz = {0.f, 0.f, 0.f, 0.f};
#pragma unroll
  for (int j = 0; j < 12; ++j) { acc0[j] = zz; acc1[j] = zz; }

  auto STAGE = [&](int p, int t) {  // exactly 6 gll per wave
    char* Aslab = smem + p * 36864 + w * 4096;
#pragma unroll
    for (int i = 0; i < 4; ++i) {
      int fo = t * 32 + (acolB[i] >> 2);
      if (fo >= NN) fo = 0;  // K-tail: B k-slots >= 10000 are zeroed
      __builtin_amdgcn_global_load_lds((const void*)(adj + (size_t)arow[i] * NN + fo),
                                       (void*)(Aslab + i * 1024 + lane * 16), 16, 0, 0);
    }
    char* Bar = smem + p * 36864 + 24576;
#pragma unroll
    for (int f = 0; f < 2; ++f) {
      int fr = w * 2 + f;
      __builtin_amdgcn_global_load_lds(
          (const void*)(PB + (size_t)t * 6144 + fr * 512 + lane * 8),
          (void*)(Bar + fr * 1024 + lane * 16), 16, 0, 0);
    }
  };

  int swz = (r0 & 7) << 4;
  auto MM = [&](int p) {
    const char* Aslab = smem + p * 36864 + w * 4096;
    const char* Bar = smem + p * 36864 + 24576;
    float4 a00 = *(const float4*)(Aslab + r0 * 128 + ((kq * 32) ^ swz));
    float4 a01 = *(const float4*)(Aslab + r0 * 128 + ((kq * 32 + 16) ^ swz));
    float4 a10 = *(const float4*)(Aslab + (r0 + 16) * 128 + ((kq * 32) ^ swz));
    float4 a11 = *(const float4*)(Aslab + (r0 + 16) * 128 + ((kq * 32 + 16) ^ swz));
    short8v fa0 = cvt8(a00, a01);
    short8v fa1 = cvt8(a10, a11);
#pragma unroll
    for (int j = 0; j < 12; ++j) {
      short8v b = *(const short8v*)(Bar + j * 1024 + lane * 16);
      acc0[j] = __builtin_amdgcn_mfma_f32_16x16x32_bf16(fa0, b, acc0[j], 0, 0, 0);
      acc1[j] = __builtin_amdgcn_mfma_f32_16x16x32_bf16(fa1, b, acc1[j], 0, 0, 0);
    }
  };

  STAGE(0, t0);
  if (ns > 1) STAGE(1, t0 + 1);
  for (int i = 0; i < ns; ++i) {
    if (i < ns - 1) asm volatile("s_waitcnt vmcnt(6)" ::: "memory");
    else            asm volatile("s_waitcnt vmcnt(0)" ::: "memory");
    __builtin_amdgcn_s_barrier();          // all waves' step-i loads landed
    __builtin_amdgcn_sched_barrier(0);     // pin ds_reads after the barrier
    MM(i & 1);
    asm volatile("s_waitcnt lgkmcnt(0)" ::: "memory");  // own ds_reads drained
    __builtin_amdgcn_sched_barrier(0);
    __builtin_amdgcn_s_barrier();          // all waves done reading buf[i&1]
    __builtin_amdgcn_sched_barrier(0);
    if (i + 2 < ns) STAGE(i & 1, t0 + i + 2);
  }

  // epilogue: D layout col(lane&15)=feature, row(M)=kq*4+r
  size_t cbase = (size_t)bc * ((size_t)NN * 192);
  int drow = kq * 4;
#pragma unroll
  for (int j = 0; j < 12; ++j) {
#pragma unroll
    for (int r = 0; r < 4; ++r) {
      int rw0 = R0w + drow + r;
      int rw1 = R0w + 16 + drow + r;
      if (rw0 < NN)
        partC[cbase + (size_t)rw0 * 192 + j * 16 + r0] = (unsigned short)f2bf(acc0[j][r]);
      if (rw1 < NN)
        partC[cbase + (size_t)rw1 * 192 + j * 16 + r0] = (unsigned short)f2bf(acc1[j][r]);
    }
  }
}

// ---------------- K6: reduce partials + hyperbolic epilogue -> h ----------------
__global__ __launch_bounds__(256) void k_epi(const unsigned short* __restrict__ partC,
                                             float* __restrict__ outH, int NC) {
  int gid = blockIdx.x * 256 + threadIdx.x;
  if (gid >= NN * 12) return;
  int n = gid / 12, t = gid - n * 12;
  float sup[16];
#pragma unroll
  for (int d = 0; d < 16; ++d) sup[d] = 0.f;
  for (int c = 0; c < NC; ++c) {
    const short8v* p8 = (const short8v*)(partC + (size_t)c * (NN * 192) + (size_t)n * 192 + t * 16);
    short8v lo = p8[0], hi = p8[1];
#pragma unroll
    for (int d = 0; d < 8; ++d) sup[d] += bf2f((unsigned short)lo[d]);
#pragma unroll
    for (int d = 0; d < 8; ++d) sup[8 + d] += bf2f((unsigned short)hi[d]);
  }
  // agg = proj(expmap0(sup))
  float nn_ = 0.f;
#pragma unroll
  for (int d = 0; d < 16; ++d) nn_ += sup[d] * sup[d];
  nn_ = fmaxf(sqrtf(nn_), 1e-15f);
  float s0 = tanhf(nn_) / nn_;
#pragma unroll
  for (int d = 0; d < 16; ++d) sup[d] *= s0;
  proj16(sup);
  // relu(logmap0(agg))
  float pn = 0.f;
#pragma unroll
  for (int d = 0; d < 16; ++d) pn += sup[d] * sup[d];
  pn = fmaxf(sqrtf(pn), 1e-15f);
  float sl = artanh_(pn) / pn;
#pragma unroll
  for (int d = 0; d < 16; ++d) sup[d] = fmaxf(sup[d] * sl, 0.f);
  // proj(expmap0(...))
  float un = 0.f;
#pragma unroll
  for (int d = 0; d < 16; ++d) un += sup[d] * sup[d];
  un = fmaxf(sqrtf(un), 1e-15f);
  float se = tanhf(un) / un;
#pragma unroll
  for (int d = 0; d < 16; ++d) sup[d] *= se;
  proj16(sup);
  float* hp = outH + (size_t)n * 192 + t;  // h[n][d][t]
#pragma unroll
  for (int d = 0; d < 16; ++d) hp[d * 12] = sup[d];
}

extern "C" void kernel_launch(void* const* d_in, const int* in_sizes, int n_in,
                              void* d_out, int out_size, void* d_ws, size_t ws_size,
                              hipStream_t stream) {
  const float* x   = (const float*)d_in[0];
  const float* adj = (const float*)d_in[1];
  const float* U1a = (const float*)d_in[2];
  const float* U2a = (const float*)d_in[3];
  const float* U3a = (const float*)d_in[4];
  const float* bea = (const float*)d_in[5];
  const float* Vea = (const float*)d_in[6];
  const float* U1b = (const float*)d_in[7];
  const float* U2b = (const float*)d_in[8];
  const float* U3b = (const float*)d_in[9];
  const float* beb = (const float*)d_in[10];
  const float* Veb = (const float*)d_in[11];
  const float* w1  = (const float*)d_in[12];
  const float* b1  = (const float*)d_in[13];
  const float* w2  = (const float*)d_in[14];
  const float* b2  = (const float*)d_in[15];
  const float* hw  = (const float*)d_in[16];
  const float* hb  = (const float*)d_in[17];
  float* outF = (float*)d_out;
  float* outH = (float*)d_out + 1920000;

  char* ws = (char*)d_ws;
  size_t off = 0;
  auto alloc = [&](size_t bytes) {
    char* p = ws + off;
    off = (off + bytes + 255) & ~(size_t)255;
    return p;
  };
  float* rhsA   = (float*)alloc((size_t)12 * NN * 4);
  float* rhsB   = (float*)alloc((size_t)12 * NN * 4);
  float* partAa = (float*)alloc(160 * 192 * 4);
  float* partAb = (float*)alloc(160 * 192 * 4);
  float* partMa = (float*)alloc(80 * 192 * 4);
  float* partMb = (float*)alloc(80 * 192 * 4);
  float* tAa    = (float*)alloc(144 * 4);
  float* tAb    = (float*)alloc(144 * 4);
  unsigned short* PB = (unsigned short*)alloc((size_t)324 * 6144 * 2);  // padded to 324 steps
  size_t chunkB = (size_t)NN * 192 * 2;
  size_t avail = (ws_size > off) ? (ws_size - off) : 0;
  int NC = (int)(avail / chunkB);
  if (NC > 10) NC = 10;
  if (NC < 1) NC = 1;
  unsigned short* partC = (unsigned short*)(ws + off);
  int S = (313 + NC - 1) / NC;

  (void)hipFuncSetAttribute((const void*)k_gemm,
                            hipFuncAttributeMaxDynamicSharedMemorySize, 73728);

  k_attn1<<<160, 192, 0, stream>>>(x, U1a, U3a, U1b, U3b, rhsA, rhsB, partAa, partAb, PB);
  k_attn2<<<80, 192, 0, stream>>>(U2a, U2b, rhsA, rhsB, partMa, partMb, PB);
  k_attn3<<<1, 192, 0, stream>>>(partAa, partAb, partMa, partMb, bea, Vea, beb, Veb, tAa, tAb);
  k_node<<<625, 192, 0, stream>>>(x, tAa, tAb, w1, b1, w2, b2, hw, hb, outF, PB);
  k_gemm<<<53 * NC, 384, 73728, stream>>>(adj, PB, partC, S);
  k_epi<<<(NN * 12 + 255) / 256, 256, 0, stream>>>(partC, outH, NC);
}

// Round 10
// 241.539 us; speedup vs baseline: 1.3329x; 1.1310x over previous
//
#include <hip/hip_runtime.h>
#include <hip/hip_bf16.h>
#include <math.h>

#define NN 10000

typedef __attribute__((ext_vector_type(4))) float f32x4;
typedef __attribute__((ext_vector_type(8))) short short8v;

__device__ __forceinline__ short f2bf(float f) {
  union { float f; unsigned u; } v; v.f = f;
  unsigned u = v.u + 0x7FFFu + ((v.u >> 16) & 1u);  // RNE
  return (short)(u >> 16);
}
__device__ __forceinline__ float bf2f(unsigned short h) {
  union { unsigned u; float f; } v; v.u = ((unsigned)h) << 16;
  return v.f;
}
__device__ __forceinline__ float artanh_(float xx) {
  xx = fminf(fmaxf(xx, -1.f + 1e-7f), 1.f - 1e-7f);
  return atanhf(xx);
}
__device__ __forceinline__ void proj16(float* v) {
  float s = 0.f;
#pragma unroll
  for (int i = 0; i < 16; ++i) s += v[i] * v[i];
  float n = fmaxf(sqrtf(s), 1e-15f);
  const float mxn = 1.0f - 4e-3f;
  if (n > mxn) {
    float sc = mxn / n;
#pragma unroll
    for (int i = 0; i < 16; ++i) v[i] *= sc;
  }
}
__device__ __forceinline__ short8v cvt8(const float4& u, const float4& w) {
  union { __hip_bfloat162 h; unsigned u32; } c0, c1, c2, c3;
  c0.h = __float22bfloat162_rn(make_float2(u.x, u.y));
  c1.h = __float22bfloat162_rn(make_float2(u.z, u.w));
  c2.h = __float22bfloat162_rn(make_float2(w.x, w.y));
  c3.h = __float22bfloat162_rn(make_float2(w.z, w.w));
  union { unsigned v[4]; short8v s; } r;
  r.v[0] = c0.u32; r.v[1] = c1.u32; r.v[2] = c2.u32; r.v[3] = c3.u32;
  return r.s;
}

// ---------------- K1: pass over x -> rhs (both branches) + partial a; zero step-312 PB tail ----------------
__global__ __launch_bounds__(192) void k_attn1(
    const float* __restrict__ x,
    const float* __restrict__ U1a, const float* __restrict__ U3a,
    const float* __restrict__ U1b, const float* __restrict__ U3b,
    float* __restrict__ rhsA, float* __restrict__ rhsB,
    float* __restrict__ partAa, float* __restrict__ partAb,
    unsigned short* __restrict__ PB) {
  __shared__ float xs[16 * 193];
  int tid = threadIdx.x;
  int f_ = tid / 12, t_ = tid - f_ * 12;
  int s_ = tid >> 4, nl_ = tid & 15;
  // zero PB pad: frag-step 312, shorts [256,512) of each of its 12 frags (k >= 10000)
  if (blockIdx.x == 79) {
    for (int i = tid; i < 3072; i += 192) {
      int tt = i >> 8, q = i & 255;
      PB[(size_t)(312 * 12 + tt) * 512 + 256 + q] = 0;
    }
  }
  float paa = 0.f, pab = 0.f;
  for (int tb = blockIdx.x; tb < 625; tb += 160) {
    int n0 = tb * 16;
    for (int i = tid; i < 16 * 192; i += 192) {
      int a = i / 192, j = i - a * 192;
      xs[a * 193 + j] = x[(size_t)(n0 + a) * 192 + j];
    }
    __syncthreads();
    float ra = 0.f, rb = 0.f;
#pragma unroll
    for (int f = 0; f < 16; ++f) {
      float xv = xs[nl_ * 193 + f * 12 + s_];
      ra += xv * U3a[f];
      rb += xv * U3b[f];
    }
    rhsA[s_ * NN + n0 + nl_] = ra;
    rhsB[s_ * NN + n0 + nl_] = rb;
#pragma unroll
    for (int nl = 0; nl < 16; ++nl) {
      float xv = xs[nl * 193 + f_ * 12 + t_];
      paa += xv * U1a[n0 + nl];
      pab += xv * U1b[n0 + nl];
    }
    __syncthreads();
  }
  partAa[blockIdx.x * 192 + tid] = paa;
  partAb[blockIdx.x * 192 + tid] = pab;
}

// ---------------- K2: M[f,s] partials ----------------
__global__ __launch_bounds__(192) void k_attn2(
    const float* __restrict__ U2a, const float* __restrict__ U2b,
    const float* __restrict__ rhsA, const float* __restrict__ rhsB,
    float* __restrict__ partMa, float* __restrict__ partMb) {
  int tid = threadIdx.x;
  int f = tid / 12, s = tid - f * 12;
  int nA = blockIdx.x * 125, nE = nA + 125;
  float ma = 0.f, mb = 0.f;
  for (int n = nA; n < nE; ++n) {
    ma += U2a[f * NN + n] * rhsA[s * NN + n];
    mb += U2b[f * NN + n] * rhsB[s * NN + n];
  }
  partMa[blockIdx.x * 192 + tid] = ma;
  partMb[blockIdx.x * 192 + tid] = mb;
}

// ---------------- K3: reduce partials, product, E, softmax -> tA (both) ----------------
__global__ __launch_bounds__(192) void k_attn3(
    const float* __restrict__ partAa, const float* __restrict__ partAb,
    const float* __restrict__ partMa, const float* __restrict__ partMb,
    const float* __restrict__ beA, const float* __restrict__ VeA,
    const float* __restrict__ beB, const float* __restrict__ VeB,
    float* __restrict__ tAa, float* __restrict__ tAb) {
  __shared__ float aa[192], ab[192], Ma[192], Mb[192];
  __shared__ float spA[144], spB[144], EA[144], EB[144];
  int tid = threadIdx.x;
  float s1 = 0.f, s2 = 0.f, s3 = 0.f, s4 = 0.f;
  for (int b = 0; b < 160; ++b) { s1 += partAa[b * 192 + tid]; s2 += partAb[b * 192 + tid]; }
  for (int b = 0; b < 80; ++b) { s3 += partMa[b * 192 + tid]; s4 += partMb[b * 192 + tid]; }
  aa[tid] = s1; ab[tid] = s2; Ma[tid] = s3; Mb[tid] = s4;
  __syncthreads();
  if (tid < 144) {
    int j = tid / 12, s = tid - j * 12;
    float pa = 0.f, pb = 0.f;
#pragma unroll
    for (int f = 0; f < 16; ++f) {
      pa += aa[f * 12 + j] * Ma[f * 12 + s];
      pb += ab[f * 12 + j] * Mb[f * 12 + s];
    }
    spA[tid] = 1.f / (1.f + expf(-(pa + beA[tid])));
    spB[tid] = 1.f / (1.f + expf(-(pb + beB[tid])));
  }
  __syncthreads();
  if (tid < 144) {
    int i = tid / 12, s = tid - i * 12;
    float ea = 0.f, eb = 0.f;
#pragma unroll
    for (int j = 0; j < 12; ++j) {
      ea += VeA[i * 12 + j] * spA[j * 12 + s];
      eb += VeB[i * 12 + j] * spB[j * 12 + s];
    }
    EA[tid] = ea; EB[tid] = eb;
  }
  __syncthreads();
  if (tid < 144) {
    int s = tid % 12;
    float ma = -1e30f, mb = -1e30f;
#pragma unroll
    for (int k = 0; k < 12; ++k) { ma = fmaxf(ma, EA[k * 12 + s]); mb = fmaxf(mb, EB[k * 12 + s]); }
    float da = 0.f, db = 0.f;
#pragma unroll
    for (int k = 0; k < 12; ++k) { da += expf(EA[k * 12 + s] - ma); db += expf(EB[k * 12 + s] - mb); }
    tAa[tid] = expf(EA[tid] - ma) / da;
    tAb[tid] = expf(EB[tid] - mb) / db;
  }
}

// ---------------- K4: per-node x_tat + conv (both) + hyperbolic -> PB (lane-ordered B frags), outF ----------------
__global__ __launch_bounds__(192) void k_node(
    const float* __restrict__ x,
    const float* __restrict__ tAa_g, const float* __restrict__ tAb_g,
    const float* __restrict__ w1g, const float* __restrict__ b1g,
    const float* __restrict__ w2g, const float* __restrict__ b2g,
    const float* __restrict__ hwg, const float* __restrict__ hbg,
    float* __restrict__ outF, unsigned short* __restrict__ PB) {
  __shared__ float xs[16 * 193], tbuf[16 * 193];
  __shared__ float tAa[144], tAb[144], w1[768], w2[768];
  __shared__ float cb1[16], cb2[16], hw[256], hbr[16];
  int tid = threadIdx.x;
  int nl = tid & 15, tt = tid >> 4;
  int n0 = blockIdx.x * 16;
  for (int i = tid; i < 144; i += 192) { tAa[i] = tAa_g[i]; tAb[i] = tAb_g[i]; }
  for (int i = tid; i < 768; i += 192) { w1[i] = w1g[i]; w2[i] = w2g[i]; }
  for (int i = tid; i < 256; i += 192) hw[i] = hwg[i];
  if (tid < 16) { cb1[tid] = b1g[tid]; cb2[tid] = b2g[tid]; hbr[tid] = hbg[tid]; }
  for (int i = tid; i < 16 * 192; i += 192) {
    int a = i / 192, j = i - a * 192;
    xs[a * 193 + j] = x[(size_t)(n0 + a) * 192 + j];
  }
  __syncthreads();

  float z[16];
  // ======== branch b (second attention -> conv2 -> final_output) ========
#pragma unroll
  for (int f = 0; f < 16; ++f) {
    float v = 0.f;
#pragma unroll
    for (int s = 0; s < 12; ++s) v += xs[nl * 193 + f * 12 + s] * tAb[s * 12 + tt];
    tbuf[nl * 193 + f * 12 + tt] = v;
  }
  __syncthreads();
#pragma unroll
  for (int o = 0; o < 16; ++o) z[o] = cb2[o];
#pragma unroll
  for (int k = 0; k < 3; ++k) {
    int t2 = tt + k - 1;
    if (t2 >= 0 && t2 < 12) {
#pragma unroll
      for (int i = 0; i < 16; ++i) {
        float xv = tbuf[nl * 193 + i * 12 + t2];
#pragma unroll
        for (int o = 0; o < 16; ++o) z[o] += xv * w2[o * 48 + i * 3 + k];
      }
    }
  }
  {
    float* op = outF + (size_t)tt * (NN * 16) + (size_t)(n0 + nl) * 16;
#pragma unroll
    for (int o = 0; o < 16; ++o) op[o] = z[o];
  }
  __syncthreads();

  // ======== branch a (first attention -> conv1 -> hyperbolic -> xt) ========
#pragma unroll
  for (int f = 0; f < 16; ++f) {
    float v = 0.f;
#pragma unroll
    for (int s = 0; s < 12; ++s) v += xs[nl * 193 + f * 12 + s] * tAa[s * 12 + tt];
    tbuf[nl * 193 + f * 12 + tt] = v;
  }
  __syncthreads();
#pragma unroll
  for (int o = 0; o < 16; ++o) z[o] = cb1[o];
#pragma unroll
  for (int k = 0; k < 3; ++k) {
    int t2 = tt + k - 1;
    if (t2 >= 0 && t2 < 12) {
#pragma unroll
      for (int i = 0; i < 16; ++i) {
        float xv = tbuf[nl * 193 + i * 12 + t2];
#pragma unroll
        for (int o = 0; o < 16; ++o) z[o] += xv * w1[o * 48 + i * 3 + k];
      }
    }
  }
  // x_hyp = proj(expmap0(z))
  float nz = 0.f;
#pragma unroll
  for (int i = 0; i < 16; ++i) nz += z[i] * z[i];
  nz = fmaxf(sqrtf(nz), 1e-15f);
  float sc0 = tanhf(nz) / nz;
#pragma unroll
  for (int i = 0; i < 16; ++i) z[i] *= sc0;
  proj16(z);
  // mobius_matvec(hgc_w, x_hyp)
  float xn = 0.f;
#pragma unroll
  for (int i = 0; i < 16; ++i) xn += z[i] * z[i];
  xn = fmaxf(sqrtf(xn), 1e-15f);
  float mx[16];
#pragma unroll
  for (int d = 0; d < 16; ++d) {
    float v = 0.f;
#pragma unroll
    for (int f = 0; f < 16; ++f) v += z[f] * hw[d * 16 + f];
    mx[d] = v;
  }
  float mxr = 0.f;
#pragma unroll
  for (int d = 0; d < 16; ++d) mxr += mx[d] * mx[d];
  mxr = sqrtf(mxr);
  float mxn = fmaxf(mxr, 1e-15f);
  float rs = tanhf(mxn / xn * artanh_(xn)) / mxn;
  if (mxr == 0.f) rs = 0.f;
#pragma unroll
  for (int d = 0; d < 16; ++d) mx[d] *= rs;
  proj16(mx);
  // hyp_b = proj(expmap0(hgc_b))
  float hb[16];
  float bn = 0.f;
#pragma unroll
  for (int i = 0; i < 16; ++i) { hb[i] = hbr[i]; bn += hb[i] * hb[i]; }
  bn = fmaxf(sqrtf(bn), 1e-15f);
  float sb = tanhf(bn) / bn;
#pragma unroll
  for (int i = 0; i < 16; ++i) hb[i] *= sb;
  proj16(hb);
  // res = proj(mobius_add(mx, hb))
  float x2 = 0.f, y2 = 0.f, xy = 0.f;
#pragma unroll
  for (int i = 0; i < 16; ++i) { x2 += mx[i] * mx[i]; y2 += hb[i] * hb[i]; xy += mx[i] * hb[i]; }
  float ca = 1.f + 2.f * xy + y2;
  float cbv = 1.f - x2;
  float den = fmaxf(1.f + 2.f * xy + x2 * y2, 1e-15f);
#pragma unroll
  for (int i = 0; i < 16; ++i) mx[i] = (ca * mx[i] + cbv * hb[i]) / den;
  proj16(mx);
  // xt = logmap0(res) -> PB in MFMA lane order:
  // PB[frag*512 + lane*8 + j] = B[k=(lane>>4)*8+j][col=lane&15]
  float pn = 0.f;
#pragma unroll
  for (int i = 0; i < 16; ++i) pn += mx[i] * mx[i];
  pn = fmaxf(sqrtf(pn), 1e-15f);
  float sl = artanh_(pn) / pn;
  {
    int nn2 = n0 + nl;
    int s = nn2 >> 5, c = nn2 & 31;
    unsigned short* pp = PB + (size_t)(s * 12 + tt) * 512 + (c >> 3) * 128 + (c & 7);
#pragma unroll
    for (int d = 0; d < 16; ++d)
      pp[d * 8] = (unsigned short)f2bf(mx[d] * sl);
  }
}

// ---------------- K5: sup = adj @ xt — 128-tile, A 3-deep / B 2-deep LDS, counted vmcnt, raw barriers ----
// blockIdx = bc*79 + rt ; 4 waves x 32 rows ; K-steps t in [bc*S, min(313,bc*S+S))
// Per step per thread: 3 B-gll + 4 A-gll. Issue order/iter: B(t+1)[3], A(t+2)[4].
// vmcnt(11) before barrier guarantees A(t)+B(t) landed (A(t) precedes B(t) in FIFO).
__global__ __launch_bounds__(256, 2) void k_gemm(
    const float* __restrict__ adj, const unsigned short* __restrict__ PB,
    unsigned short* __restrict__ partC, int S) {
  extern __shared__ char smem[];  // A: 3 x 16KB at p*16384 ; B: 2 x 12KB at 49152+q*12288
  int bc = blockIdx.x / 79;
  int rt = blockIdx.x - bc * 79;
  int t0 = bc * S, t1 = min(313, t0 + S);
  int ns = t1 - t0;
  int tid = threadIdx.x;
  int lane = tid & 63, w = tid >> 6;
  int r0 = lane & 15, kq = lane >> 4;
  int R0 = rt * 128 + w * 32;

  // A staging map (as R5): li16 = c*256+tid; row = li16>>3; off = (li16&7)*16; swizzle per row
  int arow[4], aoffF[4];
#pragma unroll
  for (int c = 0; c < 4; ++c) {
    int li = c * 256 + tid;
    int row = li >> 3;
    int off = (li & 7) * 16;
    int xa = ((row & 3) << 5) | ((row & 4) << 2);
    arow[c] = min(rt * 128 + row, NN - 1);
    aoffF[c] = (off ^ xa) >> 2;
  }

  f32x4 acc0[12], acc1[12];
  f32x4 zz = {0.f, 0.f, 0.f, 0.f};
#pragma unroll
  for (int j = 0; j < 12; ++j) { acc0[j] = zz; acc1[j] = zz; }

  auto STAGE_B = [&](int q, int t) {  // 3 gll
    const unsigned short* gb = PB + (size_t)t * 6144;
    char* dst = smem + 49152 + q * 12288;
#pragma unroll
    for (int c = 0; c < 3; ++c) {
      int li = c * 256 + tid;
      __builtin_amdgcn_global_load_lds((const void*)(gb + li * 8),
                                       (void*)(dst + li * 16), 16, 0, 0);
    }
  };
  auto STAGE_A = [&](int p, int t) {  // 4 gll
    char* dst = smem + p * 16384;
#pragma unroll
    for (int c = 0; c < 4; ++c) {
      int li = c * 256 + tid;
      int fo = t * 32 + aoffF[c];
      if (fo >= NN) fo = 0;  // K tail: logical slots multiply zeroed B
      __builtin_amdgcn_global_load_lds((const void*)(adj + (size_t)arow[c] * NN + fo),
                                       (void*)(dst + li * 16), 16, 0, 0);
    }
  };

  int xr = ((r0 & 3) << 5) | ((r0 & 4) << 2);  // read-side swizzle (same for r0 and r0+16)
  auto MM = [&](int t) {
    const char* Ab = smem + (t % 3) * 16384;
    const char* Bb = smem + 49152 + (t & 1) * 12288;
    float4 a00 = *(const float4*)(Ab + r0 * 128 + ((kq * 32 + 0) ^ xr));
    float4 a01 = *(const float4*)(Ab + r0 * 128 + ((kq * 32 + 16) ^ xr));
    float4 a10 = *(const float4*)(Ab + (r0 + 16) * 128 + ((kq * 32 + 0) ^ xr));
    float4 a11 = *(const float4*)(Ab + (r0 + 16) * 128 + ((kq * 32 + 16) ^ xr));
    short8v fa0 = cvt8(a00, a01);
    short8v fa1 = cvt8(a10, a11);
#pragma unroll
    for (int j = 0; j < 12; ++j) {
      short8v b = *(const short8v*)(Bb + j * 1024 + lane * 16);
      acc0[j] = __builtin_amdgcn_mfma_f32_16x16x32_bf16(fa0, b, acc0[j], 0, 0, 0);
      acc1[j] = __builtin_amdgcn_mfma_f32_16x16x32_bf16(fa1, b, acc1[j], 0, 0, 0);
    }
  };

  // prologue: B(0), A(0), A(1)   (A(t) must precede B(t) in FIFO for t>=1: A(1) here, B(1) in iter 0)
  STAGE_B(0, t0);
  STAGE_A(0, t0);
  if (ns > 1) STAGE_A(1 % 3, t0 + 1);

  for (int i = 0; i < ns; ++i) {
    if (i + 1 < ns) STAGE_B((i + 1) & 1, t0 + i + 1);
    if (i + 2 < ns) STAGE_A((i + 2) % 3, t0 + i + 2);
    // wait for step-i's A+B: newer loads = 4*(i+1<ns ? A(i+1):0 cnt 4) + 3*(i+1<ns) + 4*(i+2<ns)
    if (i + 2 < ns)      asm volatile("s_waitcnt vmcnt(11)" ::: "memory");
    else if (i + 1 < ns) asm volatile("s_waitcnt vmcnt(7)" ::: "memory");
    else                 asm volatile("s_waitcnt vmcnt(0)" ::: "memory");
    __builtin_amdgcn_sched_barrier(0);
    __builtin_amdgcn_s_barrier();        // block-wide: all waves' step-i loads landed
    MM(i);
    asm volatile("s_waitcnt lgkmcnt(0)" ::: "memory");  // own LDS reads retired
    __builtin_amdgcn_sched_barrier(0);
    __builtin_amdgcn_s_barrier();        // all waves done reading step-i buffers
  }

  // epilogue: D layout col(lane&15)=feature, row(M)=kq*4+r
  size_t cbase = (size_t)bc * ((size_t)NN * 192);
  int drow = kq * 4;
#pragma unroll
  for (int j = 0; j < 12; ++j) {
#pragma unroll
    for (int r = 0; r < 4; ++r) {
      int rw0 = R0 + drow + r;
      int rw1 = R0 + 16 + drow + r;
      if (rw0 < NN)
        partC[cbase + (size_t)rw0 * 192 + j * 16 + r0] = (unsigned short)f2bf(acc0[j][r]);
      if (rw1 < NN)
        partC[cbase + (size_t)rw1 * 192 + j * 16 + r0] = (unsigned short)f2bf(acc1[j][r]);
    }
  }
}

// ---------------- K6: reduce partials + hyperbolic epilogue -> h ----------------
__global__ __launch_bounds__(256) void k_epi(const unsigned short* __restrict__ partC,
                                             float* __restrict__ outH, int NC) {
  int gid = blockIdx.x * 256 + threadIdx.x;
  if (gid >= NN * 12) return;
  int n = gid / 12, t = gid - n * 12;
  float sup[16];
#pragma unroll
  for (int d = 0; d < 16; ++d) sup[d] = 0.f;
  for (int c = 0; c < NC; ++c) {
    const short8v* p8 = (const short8v*)(partC + (size_t)c * (NN * 192) + (size_t)n * 192 + t * 16);
    short8v lo = p8[0], hi = p8[1];
#pragma unroll
    for (int d = 0; d < 8; ++d) sup[d] += bf2f((unsigned short)lo[d]);
#pragma unroll
    for (int d = 0; d < 8; ++d) sup[8 + d] += bf2f((unsigned short)hi[d]);
  }
  // agg = proj(expmap0(sup))
  float nn_ = 0.f;
#pragma unroll
  for (int d = 0; d < 16; ++d) nn_ += sup[d] * sup[d];
  nn_ = fmaxf(sqrtf(nn_), 1e-15f);
  float s0 = tanhf(nn_) / nn_;
#pragma unroll
  for (int d = 0; d < 16; ++d) sup[d] *= s0;
  proj16(sup);
  // relu(logmap0(agg))
  float pn = 0.f;
#pragma unroll
  for (int d = 0; d < 16; ++d) pn += sup[d] * sup[d];
  pn = fmaxf(sqrtf(pn), 1e-15f);
  float sl = artanh_(pn) / pn;
#pragma unroll
  for (int d = 0; d < 16; ++d) sup[d] = fmaxf(sup[d] * sl, 0.f);
  // proj(expmap0(...))
  float un = 0.f;
#pragma unroll
  for (int d = 0; d < 16; ++d) un += sup[d] * sup[d];
  un = fmaxf(sqrtf(un), 1e-15f);
  float se = tanhf(un) / un;
#pragma unroll
  for (int d = 0; d < 16; ++d) sup[d] *= se;
  proj16(sup);
  float* hp = outH + (size_t)n * 192 + t;  // h[n][d][t]
#pragma unroll
  for (int d = 0; d < 16; ++d) hp[d * 12] = sup[d];
}

extern "C" void kernel_launch(void* const* d_in, const int* in_sizes, int n_in,
                              void* d_out, int out_size, void* d_ws, size_t ws_size,
                              hipStream_t stream) {
  const float* x   = (const float*)d_in[0];
  const float* adj = (const float*)d_in[1];
  const float* U1a = (const float*)d_in[2];
  const float* U2a = (const float*)d_in[3];
  const float* U3a = (const float*)d_in[4];
  const float* bea = (const float*)d_in[5];
  const float* Vea = (const float*)d_in[6];
  const float* U1b = (const float*)d_in[7];
  const float* U2b = (const float*)d_in[8];
  const float* U3b = (const float*)d_in[9];
  const float* beb = (const float*)d_in[10];
  const float* Veb = (const float*)d_in[11];
  const float* w1  = (const float*)d_in[12];
  const float* b1  = (const float*)d_in[13];
  const float* w2  = (const float*)d_in[14];
  const float* b2  = (const float*)d_in[15];
  const float* hw  = (const float*)d_in[16];
  const float* hb  = (const float*)d_in[17];
  float* outF = (float*)d_out;
  float* outH = (float*)d_out + 1920000;

  char* ws = (char*)d_ws;
  size_t off = 0;
  auto alloc = [&](size_t bytes) {
    char* p = ws + off;
    off = (off + bytes + 255) & ~(size_t)255;
    return p;
  };
  float* rhsA   = (float*)alloc((size_t)12 * NN * 4);
  float* rhsB   = (float*)alloc((size_t)12 * NN * 4);
  float* partAa = (float*)alloc(160 * 192 * 4);
  float* partAb = (float*)alloc(160 * 192 * 4);
  float* partMa = (float*)alloc(80 * 192 * 4);
  float* partMb = (float*)alloc(80 * 192 * 4);
  float* tAa    = (float*)alloc(144 * 4);
  float* tAb    = (float*)alloc(144 * 4);
  unsigned short* PB = (unsigned short*)alloc((size_t)314 * 6144 * 2);
  size_t chunkB = (size_t)NN * 192 * 2;
  size_t avail = (ws_size > off) ? (ws_size - off) : 0;
  int NC = (int)(avail / chunkB);
  if (NC > 8) NC = 8;
  if (NC < 1) NC = 1;
  unsigned short* partC = (unsigned short*)(ws + off);
  int S = (313 + NC - 1) / NC;

  (void)hipFuncSetAttribute((const void*)k_gemm,
                            hipFuncAttributeMaxDynamicSharedMemorySize, 73728);

  k_attn1<<<160, 192, 0, stream>>>(x, U1a, U3a, U1b, U3b, rhsA, rhsB, partAa, partAb, PB);
  k_attn2<<<80, 192, 0, stream>>>(U2a, U2b, rhsA, rhsB, partMa, partMb);
  k_attn3<<<1, 192, 0, stream>>>(partAa, partAb, partMa, partMb, bea, Vea, beb, Veb, tAa, tAb);
  k_node<<<625, 192, 0, stream>>>(x, tAa, tAb, w1, b1, w2, b2, hw, hb, outF, PB);
  k_gemm<<<79 * NC, 256, 73728, stream>>>(adj, PB, partC, S);
  k_epi<<<(NN * 12 + 255) / 256, 256, 0, stream>>>(partC, outH, NC);
}

// Round 12
// 223.603 us; speedup vs baseline: 1.4398x; 1.0802x over previous
//
#include <hip/hip_runtime.h>
#include <hip/hip_bf16.h>
#include <math.h>

#define NN 10000

typedef __attribute__((ext_vector_type(4))) float f32x4;
typedef __attribute__((ext_vector_type(8))) short short8v;

__device__ __forceinline__ short f2bf(float f) {
  union { float f; unsigned u; } v; v.f = f;
  unsigned u = v.u + 0x7FFFu + ((v.u >> 16) & 1u);  // RNE
  return (short)(u >> 16);
}
__device__ __forceinline__ float bf2f(unsigned short h) {
  union { unsigned u; float f; } v; v.u = ((unsigned)h) << 16;
  return v.f;
}
__device__ __forceinline__ float artanh_(float xx) {
  xx = fminf(fmaxf(xx, -1.f + 1e-7f), 1.f - 1e-7f);
  return atanhf(xx);
}
__device__ __forceinline__ void proj16(float* v) {
  float s = 0.f;
#pragma unroll
  for (int i = 0; i < 16; ++i) s += v[i] * v[i];
  float n = fmaxf(sqrtf(s), 1e-15f);
  const float mxn = 1.0f - 4e-3f;
  if (n > mxn) {
    float sc = mxn / n;
#pragma unroll
    for (int i = 0; i < 16; ++i) v[i] *= sc;
  }
}
__device__ __forceinline__ short8v cvt8(const float4& u, const float4& w) {
  union { __hip_bfloat162 h; unsigned u32; } c0, c1, c2, c3;
  c0.h = __float22bfloat162_rn(make_float2(u.x, u.y));
  c1.h = __float22bfloat162_rn(make_float2(u.z, u.w));
  c2.h = __float22bfloat162_rn(make_float2(w.x, w.y));
  c3.h = __float22bfloat162_rn(make_float2(w.z, w.w));
  union { unsigned v[4]; short8v s; } r;
  r.v[0] = c0.u32; r.v[1] = c1.u32; r.v[2] = c2.u32; r.v[3] = c3.u32;
  return r.s;
}

// ---------------- K1: pass over x -> rhs (both branches) + partial a; zero step-312 PB tail ----------------
__global__ __launch_bounds__(192) void k_attn1(
    const float* __restrict__ x,
    const float* __restrict__ U1a, const float* __restrict__ U3a,
    const float* __restrict__ U1b, const float* __restrict__ U3b,
    float* __restrict__ rhsA, float* __restrict__ rhsB,
    float* __restrict__ partAa, float* __restrict__ partAb,
    unsigned short* __restrict__ PB) {
  __shared__ float xs[16 * 193];
  int tid = threadIdx.x;
  int f_ = tid / 12, t_ = tid - f_ * 12;
  int s_ = tid >> 4, nl_ = tid & 15;
  // zero PB pad: frag-step 312, shorts [256,512) of each of its 12 frags (k >= 10000)
  if (blockIdx.x == 79) {
    for (int i = tid; i < 3072; i += 192) {
      int tt = i >> 8, q = i & 255;
      PB[(size_t)(312 * 12 + tt) * 512 + 256 + q] = 0;
    }
  }
  float paa = 0.f, pab = 0.f;
  for (int tb = blockIdx.x; tb < 625; tb += 160) {
    int n0 = tb * 16;
    for (int i = tid; i < 16 * 192; i += 192) {
      int a = i / 192, j = i - a * 192;
      xs[a * 193 + j] = x[(size_t)(n0 + a) * 192 + j];
    }
    __syncthreads();
    float ra = 0.f, rb = 0.f;
#pragma unroll
    for (int f = 0; f < 16; ++f) {
      float xv = xs[nl_ * 193 + f * 12 + s_];
      ra += xv * U3a[f];
      rb += xv * U3b[f];
    }
    rhsA[s_ * NN + n0 + nl_] = ra;
    rhsB[s_ * NN + n0 + nl_] = rb;
#pragma unroll
    for (int nl = 0; nl < 16; ++nl) {
      float xv = xs[nl * 193 + f_ * 12 + t_];
      paa += xv * U1a[n0 + nl];
      pab += xv * U1b[n0 + nl];
    }
    __syncthreads();
  }
  partAa[blockIdx.x * 192 + tid] = paa;
  partAb[blockIdx.x * 192 + tid] = pab;
}

// ---------------- K2: M[f,s] partials ----------------
__global__ __launch_bounds__(192) void k_attn2(
    const float* __restrict__ U2a, const float* __restrict__ U2b,
    const float* __restrict__ rhsA, const float* __restrict__ rhsB,
    float* __restrict__ partMa, float* __restrict__ partMb) {
  int tid = threadIdx.x;
  int f = tid / 12, s = tid - f * 12;
  int nA = blockIdx.x * 125, nE = nA + 125;
  float ma = 0.f, mb = 0.f;
  for (int n = nA; n < nE; ++n) {
    ma += U2a[f * NN + n] * rhsA[s * NN + n];
    mb += U2b[f * NN + n] * rhsB[s * NN + n];
  }
  partMa[blockIdx.x * 192 + tid] = ma;
  partMb[blockIdx.x * 192 + tid] = mb;
}

// ---------------- K3: reduce partials, product, E, softmax -> tA (both) ----------------
__global__ __launch_bounds__(192) void k_attn3(
    const float* __restrict__ partAa, const float* __restrict__ partAb,
    const float* __restrict__ partMa, const float* __restrict__ partMb,
    const float* __restrict__ beA, const float* __restrict__ VeA,
    const float* __restrict__ beB, const float* __restrict__ VeB,
    float* __restrict__ tAa, float* __restrict__ tAb) {
  __shared__ float aa[192], ab[192], Ma[192], Mb[192];
  __shared__ float spA[144], spB[144], EA[144], EB[144];
  int tid = threadIdx.x;
  float s1 = 0.f, s2 = 0.f, s3 = 0.f, s4 = 0.f;
  for (int b = 0; b < 160; ++b) { s1 += partAa[b * 192 + tid]; s2 += partAb[b * 192 + tid]; }
  for (int b = 0; b < 80; ++b) { s3 += partMa[b * 192 + tid]; s4 += partMb[b * 192 + tid]; }
  aa[tid] = s1; ab[tid] = s2; Ma[tid] = s3; Mb[tid] = s4;
  __syncthreads();
  if (tid < 144) {
    int j = tid / 12, s = tid - j * 12;
    float pa = 0.f, pb = 0.f;
#pragma unroll
    for (int f = 0; f < 16; ++f) {
      pa += aa[f * 12 + j] * Ma[f * 12 + s];
      pb += ab[f * 12 + j] * Mb[f * 12 + s];
    }
    spA[tid] = 1.f / (1.f + expf(-(pa + beA[tid])));
    spB[tid] = 1.f / (1.f + expf(-(pb + beB[tid])));
  }
  __syncthreads();
  if (tid < 144) {
    int i = tid / 12, s = tid - i * 12;
    float ea = 0.f, eb = 0.f;
#pragma unroll
    for (int j = 0; j < 12; ++j) {
      ea += VeA[i * 12 + j] * spA[j * 12 + s];
      eb += VeB[i * 12 + j] * spB[j * 12 + s];
    }
    EA[tid] = ea; EB[tid] = eb;
  }
  __syncthreads();
  if (tid < 144) {
    int s = tid % 12;
    float ma = -1e30f, mb = -1e30f;
#pragma unroll
    for (int k = 0; k < 12; ++k) { ma = fmaxf(ma, EA[k * 12 + s]); mb = fmaxf(mb, EB[k * 12 + s]); }
    float da = 0.f, db = 0.f;
#pragma unroll
    for (int k = 0; k < 12; ++k) { da += expf(EA[k * 12 + s] - ma); db += expf(EB[k * 12 + s] - mb); }
    tAa[tid] = expf(EA[tid] - ma) / da;
    tAb[tid] = expf(EB[tid] - mb) / db;
  }
}

// ---------------- K4: per-node x_tat + conv (both) + hyperbolic -> PB (lane-ordered B frags), outF ----------------
__global__ __launch_bounds__(192) void k_node(
    const float* __restrict__ x,
    const float* __restrict__ tAa_g, const float* __restrict__ tAb_g,
    const float* __restrict__ w1g, const float* __restrict__ b1g,
    const float* __restrict__ w2g, const float* __restrict__ b2g,
    const float* __restrict__ hwg, const float* __restrict__ hbg,
    float* __restrict__ outF, unsigned short* __restrict__ PB) {
  __shared__ float xs[16 * 193], tbuf[16 * 193];
  __shared__ float tAa[144], tAb[144], w1[768], w2[768];
  __shared__ float cb1[16], cb2[16], hw[256], hbr[16];
  int tid = threadIdx.x;
  int nl = tid & 15, tt = tid >> 4;
  int n0 = blockIdx.x * 16;
  for (int i = tid; i < 144; i += 192) { tAa[i] = tAa_g[i]; tAb[i] = tAb_g[i]; }
  for (int i = tid; i < 768; i += 192) { w1[i] = w1g[i]; w2[i] = w2g[i]; }
  for (int i = tid; i < 256; i += 192) hw[i] = hwg[i];
  if (tid < 16) { cb1[tid] = b1g[tid]; cb2[tid] = b2g[tid]; hbr[tid] = hbg[tid]; }
  for (int i = tid; i < 16 * 192; i += 192) {
    int a = i / 192, j = i - a * 192;
    xs[a * 193 + j] = x[(size_t)(n0 + a) * 192 + j];
  }
  __syncthreads();

  float z[16];
  // ======== branch b (second attention -> conv2 -> final_output) ========
#pragma unroll
  for (int f = 0; f < 16; ++f) {
    float v = 0.f;
#pragma unroll
    for (int s = 0; s < 12; ++s) v += xs[nl * 193 + f * 12 + s] * tAb[s * 12 + tt];
    tbuf[nl * 193 + f * 12 + tt] = v;
  }
  __syncthreads();
#pragma unroll
  for (int o = 0; o < 16; ++o) z[o] = cb2[o];
#pragma unroll
  for (int k = 0; k < 3; ++k) {
    int t2 = tt + k - 1;
    if (t2 >= 0 && t2 < 12) {
#pragma unroll
      for (int i = 0; i < 16; ++i) {
        float xv = tbuf[nl * 193 + i * 12 + t2];
#pragma unroll
        for (int o = 0; o < 16; ++o) z[o] += xv * w2[o * 48 + i * 3 + k];
      }
    }
  }
  {
    float* op = outF + (size_t)tt * (NN * 16) + (size_t)(n0 + nl) * 16;
#pragma unroll
    for (int o = 0; o < 16; ++o) op[o] = z[o];
  }
  __syncthreads();

  // ======== branch a (first attention -> conv1 -> hyperbolic -> xt) ========
#pragma unroll
  for (int f = 0; f < 16; ++f) {
    float v = 0.f;
#pragma unroll
    for (int s = 0; s < 12; ++s) v += xs[nl * 193 + f * 12 + s] * tAa[s * 12 + tt];
    tbuf[nl * 193 + f * 12 + tt] = v;
  }
  __syncthreads();
#pragma unroll
  for (int o = 0; o < 16; ++o) z[o] = cb1[o];
#pragma unroll
  for (int k = 0; k < 3; ++k) {
    int t2 = tt + k - 1;
    if (t2 >= 0 && t2 < 12) {
#pragma unroll
      for (int i = 0; i < 16; ++i) {
        float xv = tbuf[nl * 193 + i * 12 + t2];
#pragma unroll
        for (int o = 0; o < 16; ++o) z[o] += xv * w1[o * 48 + i * 3 + k];
      }
    }
  }
  // x_hyp = proj(expmap0(z))
  float nz = 0.f;
#pragma unroll
  for (int i = 0; i < 16; ++i) nz += z[i] * z[i];
  nz = fmaxf(sqrtf(nz), 1e-15f);
  float sc0 = tanhf(nz) / nz;
#pragma unroll
  for (int i = 0; i < 16; ++i) z[i] *= sc0;
  proj16(z);
  // mobius_matvec(hgc_w, x_hyp)
  float xn = 0.f;
#pragma unroll
  for (int i = 0; i < 16; ++i) xn += z[i] * z[i];
  xn = fmaxf(sqrtf(xn), 1e-15f);
  float mx[16];
#pragma unroll
  for (int d = 0; d < 16; ++d) {
    float v = 0.f;
#pragma unroll
    for (int f = 0; f < 16; ++f) v += z[f] * hw[d * 16 + f];
    mx[d] = v;
  }
  float mxr = 0.f;
#pragma unroll
  for (int d = 0; d < 16; ++d) mxr += mx[d] * mx[d];
  mxr = sqrtf(mxr);
  float mxn = fmaxf(mxr, 1e-15f);
  float rs = tanhf(mxn / xn * artanh_(xn)) / mxn;
  if (mxr == 0.f) rs = 0.f;
#pragma unroll
  for (int d = 0; d < 16; ++d) mx[d] *= rs;
  proj16(mx);
  // hyp_b = proj(expmap0(hgc_b))
  float hb[16];
  float bn = 0.f;
#pragma unroll
  for (int i = 0; i < 16; ++i) { hb[i] = hbr[i]; bn += hb[i] * hb[i]; }
  bn = fmaxf(sqrtf(bn), 1e-15f);
  float sb = tanhf(bn) / bn;
#pragma unroll
  for (int i = 0; i < 16; ++i) hb[i] *= sb;
  proj16(hb);
  // res = proj(mobius_add(mx, hb))
  float x2 = 0.f, y2 = 0.f, xy = 0.f;
#pragma unroll
  for (int i = 0; i < 16; ++i) { x2 += mx[i] * mx[i]; y2 += hb[i] * hb[i]; xy += mx[i] * hb[i]; }
  float ca = 1.f + 2.f * xy + y2;
  float cbv = 1.f - x2;
  float den = fmaxf(1.f + 2.f * xy + x2 * y2, 1e-15f);
#pragma unroll
  for (int i = 0; i < 16; ++i) mx[i] = (ca * mx[i] + cbv * hb[i]) / den;
  proj16(mx);
  // xt = logmap0(res) -> PB in MFMA lane order:
  // PB[frag*512 + lane*8 + j] = B[k=(lane>>4)*8+j][col=lane&15]
  float pn = 0.f;
#pragma unroll
  for (int i = 0; i < 16; ++i) pn += mx[i] * mx[i];
  pn = fmaxf(sqrtf(pn), 1e-15f);
  float sl = artanh_(pn) / pn;
  {
    int nn2 = n0 + nl;
    int s = nn2 >> 5, c = nn2 & 31;
    unsigned short* pp = PB + (size_t)(s * 12 + tt) * 512 + (c >> 3) * 128 + (c & 7);
#pragma unroll
    for (int d = 0; d < 16; ++d)
      pp[d * 8] = (unsigned short)f2bf(mx[d] * sl);
  }
}

// ---------------- K5: sup = adj @ xt — BM=256, 8 waves, all-3-deep LDS, ONE barrier/step ----------------
// grid = NC(6) x 40 row-tiles; 512 threads. Per wave per step: exactly 6 global_load_lds,
// ALL width-16 (4 A + 2 B; B = 12 chunks of 1024B, waves 4-7 issue a benign duplicate).
// LDS = 3 x 32KB A + 3 x 12KB B = 132 KB. Loop: STAGE(i+2) -> MM(i) -> lgkmcnt(0) ->
// vmcnt(6) -> barrier. Loads never drained mid-loop.
__global__ __launch_bounds__(512) void k_gemm(
    const float* __restrict__ adj, const unsigned short* __restrict__ PB,
    unsigned short* __restrict__ partC, int S) {
  extern __shared__ char smem[];  // A: 3 x 32768 at p*32768 ; B: 3 x 12288 at 98304+p*12288
  int tid = threadIdx.x;
  int w = tid >> 6, lane = tid & 63;
  int bc = blockIdx.x / 40;
  int rt = blockIdx.x - bc * 40;
  int t0 = bc * S, t1 = min(313, t0 + S);
  int ns = t1 - t0;
  int r0 = lane & 15, kq = lane >> 4;
  int R0w = rt * 256 + w * 32;

  // A staging: instr i covers wave rows 8i..8i+7, lane l -> row 8i+(l>>3), 16B at swizzled col.
  // row&7 == lane>>3 for all i, so the source swizzle offset is lane-only:
  int aoffF = (((lane & 7) * 16) ^ ((lane >> 3) << 4)) >> 2;  // float idx in 32-float window
  int arow[4];
#pragma unroll
  for (int i = 0; i < 4; ++i) arow[i] = min(R0w + i * 8 + (lane >> 3), NN - 1);

  // B chunks (width-16): 12 chunks x 1024 B; wave w -> chunk w, second = (w<4) ? 8+w : w (dup).
  int bc0 = w;
  int bc1 = (w < 4) ? (8 + w) : w;

  f32x4 acc0[12], acc1[12];
  f32x4 zz = {0.f, 0.f, 0.f, 0.f};
#pragma unroll
  for (int j = 0; j < 12; ++j) { acc0[j] = zz; acc1[j] = zz; }

  auto STAGE = [&](int p, int t) {  // exactly 6 gll per wave, all width-16
    char* Bdst = smem + 98304 + p * 12288;
    const char* Bsrc = (const char*)PB + (size_t)t * 12288;
    __builtin_amdgcn_global_load_lds((const void*)(Bsrc + bc0 * 1024 + lane * 16),
                                     (void*)(Bdst + bc0 * 1024 + lane * 16), 16, 0, 0);
    __builtin_amdgcn_global_load_lds((const void*)(Bsrc + bc1 * 1024 + lane * 16),
                                     (void*)(Bdst + bc1 * 1024 + lane * 16), 16, 0, 0);
    char* Adst = smem + p * 32768 + (w * 32) * 128;
#pragma unroll
    for (int i = 0; i < 4; ++i) {
      int fo = t * 32 + aoffF;
      if (fo >= NN) fo = 0;  // K tail: those logical slots multiply zeroed B
      __builtin_amdgcn_global_load_lds((const void*)(adj + (size_t)arow[i] * NN + fo),
                                       (void*)(Adst + i * 1024 + lane * 16), 16, 0, 0);
    }
  };

  int xr = (r0 & 7) << 4;  // read-side swizzle (rows r0 and r0+16 share r0&7)
  auto MM = [&](int p) {
    const char* Ab = smem + p * 32768 + (w * 32) * 128;
    const char* Bb = smem + 98304 + p * 12288;
    float4 a00 = *(const float4*)(Ab + r0 * 128 + ((kq * 32) ^ xr));
    float4 a01 = *(const float4*)(Ab + r0 * 128 + ((kq * 32 + 16) ^ xr));
    float4 a10 = *(const float4*)(Ab + (r0 + 16) * 128 + ((kq * 32) ^ xr));
    float4 a11 = *(const float4*)(Ab + (r0 + 16) * 128 + ((kq * 32 + 16) ^ xr));
    short8v fa0 = cvt8(a00, a01);
    short8v fa1 = cvt8(a10, a11);
#pragma unroll
    for (int j = 0; j < 12; ++j) {
      short8v b = *(const short8v*)(Bb + j * 1024 + lane * 16);
      acc0[j] = __builtin_amdgcn_mfma_f32_16x16x32_bf16(fa0, b, acc0[j], 0, 0, 0);
      acc1[j] = __builtin_amdgcn_mfma_f32_16x16x32_bf16(fa1, b, acc1[j], 0, 0, 0);
    }
  };

  // prologue: slots 0,1 <- steps t0, t0+1
  STAGE(0, t0);
  if (ns > 1) STAGE(1, t0 + 1);
  if (ns > 1) asm volatile("s_waitcnt vmcnt(6)" ::: "memory");
  else        asm volatile("s_waitcnt vmcnt(0)" ::: "memory");
  __builtin_amdgcn_sched_barrier(0);
  __builtin_amdgcn_s_barrier();
  __builtin_amdgcn_sched_barrier(0);

  for (int i = 0; i < ns; ++i) {
    if (i + 2 < ns) STAGE((i + 2) % 3, t0 + i + 2);
    MM(i % 3);
    asm volatile("s_waitcnt lgkmcnt(0)" ::: "memory");  // own LDS reads retired
    if (i + 1 < ns) {
      if (i + 2 < ns) asm volatile("s_waitcnt vmcnt(6)" ::: "memory");  // step i+1 landed
      else            asm volatile("s_waitcnt vmcnt(0)" ::: "memory");
      __builtin_amdgcn_sched_barrier(0);
      __builtin_amdgcn_s_barrier();
      __builtin_amdgcn_sched_barrier(0);
    }
  }

  // epilogue: D layout col(lane&15)=feature, row(M)=kq*4+r
  size_t cbase = (size_t)bc * ((size_t)NN * 192);
  int drow = kq * 4;
#pragma unroll
  for (int j = 0; j < 12; ++j) {
#pragma unroll
    for (int r = 0; r < 4; ++r) {
      int rw0 = R0w + drow + r;
      int rw1 = R0w + 16 + drow + r;
      if (rw0 < NN)
        partC[cbase + (size_t)rw0 * 192 + j * 16 + r0] = (unsigned short)f2bf(acc0[j][r]);
      if (rw1 < NN)
        partC[cbase + (size_t)rw1 * 192 + j * 16 + r0] = (unsigned short)f2bf(acc1[j][r]);
    }
  }
}

// ---------------- K6: reduce partials + hyperbolic epilogue -> h ----------------
__global__ __launch_bounds__(256) void k_epi(const unsigned short* __restrict__ partC,
                                             float* __restrict__ outH, int NC) {
  int gid = blockIdx.x * 256 + threadIdx.x;
  if (gid >= NN * 12) return;
  int n = gid / 12, t = gid - n * 12;
  float sup[16];
#pragma unroll
  for (int d = 0; d < 16; ++d) sup[d] = 0.f;
  for (int c = 0; c < NC; ++c) {
    const short8v* p8 = (const short8v*)(partC + (size_t)c * (NN * 192) + (size_t)n * 192 + t * 16);
    short8v lo = p8[0], hi = p8[1];
#pragma unroll
    for (int d = 0; d < 8; ++d) sup[d] += bf2f((unsigned short)lo[d]);
#pragma unroll
    for (int d = 0; d < 8; ++d) sup[8 + d] += bf2f((unsigned short)hi[d]);
  }
  // agg = proj(expmap0(sup))
  float nn_ = 0.f;
#pragma unroll
  for (int d = 0; d < 16; ++d) nn_ += sup[d] * sup[d];
  nn_ = fmaxf(sqrtf(nn_), 1e-15f);
  float s0 = tanhf(nn_) / nn_;
#pragma unroll
  for (int d = 0; d < 16; ++d) sup[d] *= s0;
  proj16(sup);
  // relu(logmap0(agg))
  float pn = 0.f;
#pragma unroll
  for (int d = 0; d < 16; ++d) pn += sup[d] * sup[d];
  pn = fmaxf(sqrtf(pn), 1e-15f);
  float sl = artanh_(pn) / pn;
#pragma unroll
  for (int d = 0; d < 16; ++d) sup[d] = fmaxf(sup[d] * sl, 0.f);
  // proj(expmap0(...))
  float un = 0.f;
#pragma unroll
  for (int d = 0; d < 16; ++d) un += sup[d] * sup[d];
  un = fmaxf(sqrtf(un), 1e-15f);
  float se = tanhf(un) / un;
#pragma unroll
  for (int d = 0; d < 16; ++d) sup[d] *= se;
  proj16(sup);
  float* hp = outH + (size_t)n * 192 + t;  // h[n][d][t]
#pragma unroll
  for (int d = 0; d < 16; ++d) hp[d * 12] = sup[d];
}

extern "C" void kernel_launch(void* const* d_in, const int* in_sizes, int n_in,
                              void* d_out, int out_size, void* d_ws, size_t ws_size,
                              hipStream_t stream) {
  const float* x   = (const float*)d_in[0];
  const float* adj = (const float*)d_in[1];
  const float* U1a = (const float*)d_in[2];
  const float* U2a = (const float*)d_in[3];
  const float* U3a = (const float*)d_in[4];
  const float* bea = (const float*)d_in[5];
  const float* Vea = (const float*)d_in[6];
  const float* U1b = (const float*)d_in[7];
  const float* U2b = (const float*)d_in[8];
  const float* U3b = (const float*)d_in[9];
  const float* beb = (const float*)d_in[10];
  const float* Veb = (const float*)d_in[11];
  const float* w1  = (const float*)d_in[12];
  const float* b1  = (const float*)d_in[13];
  const float* w2  = (const float*)d_in[14];
  const float* b2  = (const float*)d_in[15];
  const float* hw  = (const float*)d_in[16];
  const float* hb  = (const float*)d_in[17];
  float* outF = (float*)d_out;
  float* outH = (float*)d_out + 1920000;

  char* ws = (char*)d_ws;
  size_t off = 0;
  auto alloc = [&](size_t bytes) {
    char* p = ws + off;
    off = (off + bytes + 255) & ~(size_t)255;
    return p;
  };
  float* rhsA   = (float*)alloc((size_t)12 * NN * 4);
  float* rhsB   = (float*)alloc((size_t)12 * NN * 4);
  float* partAa = (float*)alloc(160 * 192 * 4);
  float* partAb = (float*)alloc(160 * 192 * 4);
  float* partMa = (float*)alloc(80 * 192 * 4);
  float* partMb = (float*)alloc(80 * 192 * 4);
  float* tAa    = (float*)alloc(144 * 4);
  float* tAb    = (float*)alloc(144 * 4);
  unsigned short* PB = (unsigned short*)alloc((size_t)314 * 6144 * 2);
  const int NC = 6;                 // 40 x 6 = 240 blocks -> single scheduling round
  unsigned short* partC = (unsigned short*)alloc((size_t)NC * NN * 192 * 2);
  (void)ws_size;
  int S = (313 + NC - 1) / NC;      // 53

  (void)hipFuncSetAttribute((const void*)k_gemm,
                            hipFuncAttributeMaxDynamicSharedMemorySize, 135168);

  k_attn1<<<160, 192, 0, stream>>>(x, U1a, U3a, U1b, U3b, rhsA, rhsB, partAa, partAb, PB);
  k_attn2<<<80, 192, 0, stream>>>(U2a, U2b, rhsA, rhsB, partMa, partMb);
  k_attn3<<<1, 192, 0, stream>>>(partAa, partAb, partMa, partMb, bea, Vea, beb, Veb, tAa, tAb);
  k_node<<<625, 192, 0, stream>>>(x, tAa, tAb, w1, b1, w2, b2, hw, hb, outF, PB);
  k_gemm<<<40 * NC, 512, 135168, stream>>>(adj, PB, partC, S);
  k_epi<<<(NN * 12 + 255) / 256, 256, 0, stream>>>(partC, outH, NC);
}